// Round 11
// baseline (339.720 us; speedup 1.0000x reference)
//
#include <hip/hip_runtime.h>
#include <hip/hip_bf16.h>

// All reference dtypes are float32 (verified R3): inputs const float*, output float*.

#define BATCH 2
#define NTOK 9216        // 96*96
#define CCH 64
#define DV 32
#define KS 8                          // key splits (per block; x2 waves -> eff 16)
#define KEYS_PER_BLOCK (NTOK / KS)    // 1152
#define KEYS_PER_WAVE (KEYS_PER_BLOCK / 2)  // 576 (per wave)
#define KT 32                         // keys per MFMA tile
#define NKT (KEYS_PER_WAVE / KT)      // 18 tiles per wave
#define ROWS (BATCH * NTOK)           // 18432
#define QT (ROWS / 32)                // 576 query tiles (32 q per block)
#define LOG2E 1.44269504088896340736f
#define PB 32                         // proj rows per block
#define ZTOT 152208                   // float4s to zero: l_acc+o_acc+cnt

typedef __attribute__((ext_vector_type(8))) short bf16x8;   // 8 bf16 (4 VGPRs)
typedef __attribute__((ext_vector_type(4))) float f32x4;    // MFMA C/D

__device__ __forceinline__ short f2bf(float x) {
    __hip_bfloat16 h = __float2bfloat16(x);   // RNE
    return *(short*)&h;
}
__device__ __forceinline__ float bf2f(short s) {
    unsigned u = ((unsigned)(unsigned short)s) << 16;
    return *(float*)&u;
}

// ---------------------------------------------------------------------------
// Kernel 1: projections -> MFMA-ready bf16 operands + zeroing of l/o_acc/cnt.
//  gx[row][32]: [g_hi(8) | g_lo(8) | g_hi(8) | 0]   (g pre-scaled by log2e)
//  fx[key][32]: [f_hi(8) | f_hi(8) | f_lo(8) | 0]
//  hT[b][v][k_pv]: transposed H with keys permuted within each 32-key tile:
//   np(ni) = ((ni&15)>>2)*8 + (ni&3) + ((ni>>4)&1)*4  — makes post-exp2 P
//   registers directly usable as the PV A-frag (verified R8).
// ---------------------------------------------------------------------------
__global__ __launch_bounds__(512) void proj_kernel(
    const float* __restrict__ x,
    const float* __restrict__ W1, const float* __restrict__ b1,
    const float* __restrict__ W2, const float* __restrict__ b2,
    const float* __restrict__ W3, const float* __restrict__ b3,
    short* __restrict__ fx, short* __restrict__ gx, short* __restrict__ hT,
    float4* __restrict__ zbase)
{
    __shared__ float xS[PB][CCH];        // 8 KB
    __shared__ short fgS[2][PB][32];     // 4 KB staging for fx, gx
    __shared__ short hS[32][PB + 2];     // 2.1 KB staging for hT

    const int tid = threadIdx.x;
    const int r0  = blockIdx.x * PB;     // 32-row tile, batch-aligned

    // zero l_acc + o_acc + cnt: one float4 per thread, grid covers ZTOT
    {
        int zi = blockIdx.x * 512 + tid;
        if (zi < ZTOT) zbase[zi] = make_float4(0.f, 0.f, 0.f, 0.f);
    }

    // cooperative x load: 512 threads x float4 = 32 rows x 64 floats
    ((float4*)xS)[tid] = ((const float4*)(x + (size_t)r0 * CCH))[tid];
    __syncthreads();

    // phase 1: f (tid<256) / g (tid>=256) — wave-uniform split
    {
        const int half = tid >> 8;            // 0: f, 1: g
        const int rr   = (tid & 255) >> 3;    // 0..31
        const int c    = tid & 7;             // 0..7
        const float* xr = xS[rr];
        if (half == 0) {
            float acc = b1[c];
            #pragma unroll
            for (int k = 0; k < CCH; ++k) acc += xr[k] * W1[k * 8 + c];
            short hi = f2bf(acc);
            short lo = f2bf(acc - bf2f(hi));
            fgS[0][rr][c] = hi; fgS[0][rr][c + 8] = hi;
            fgS[0][rr][c + 16] = lo; fgS[0][rr][c + 24] = 0;
        } else {
            float acc = b2[c];
            #pragma unroll
            for (int k = 0; k < CCH; ++k) acc += xr[k] * W2[k * 8 + c];
            acc *= LOG2E;                 // fold log2(e) for exp2 inner loop
            short hi = f2bf(acc);
            short lo = f2bf(acc - bf2f(hi));
            fgS[1][rr][c] = hi; fgS[1][rr][c + 8] = lo;
            fgS[1][rr][c + 16] = hi; fgS[1][rr][c + 24] = 0;
        }
    }
    // phase 2: h — thread (c = tid&31, rbase = tid>>5) covers rows rbase, rbase+16
    {
        const int c = tid & 31;
        const int rbase = tid >> 5;
        #pragma unroll
        for (int s = 0; s < 2; ++s) {
            int rr = rbase + s * 16;
            float acc = b3[c];
            #pragma unroll
            for (int k = 0; k < CCH; ++k) acc += xS[rr][k] * W3[k * 32 + c];
            int np = ((rr & 15) >> 2) * 8 + (rr & 3) + ((rr >> 4) & 1) * 4;
            hS[c][np] = f2bf(acc);
        }
    }
    __syncthreads();

    // coalesced write-out (dwords)
    ((int*)(fx + (size_t)r0 * 32))[tid] = ((const int*)fgS[0])[tid];
    ((int*)(gx + (size_t)r0 * 32))[tid] = ((const int*)fgS[1])[tid];
    {
        const int b  = r0 / NTOK;
        const int n0 = r0 - b * NTOK;
        const int c  = tid >> 4;
        const int d  = tid & 15;
        ((int*)(hT + (size_t)(b * 32 + c) * NTOK + n0))[d] = ((const int*)&hS[c][0])[d];
    }
}

// ---------------------------------------------------------------------------
// Kernel 2: MFMA flash attention with ZERO in-loop LDS (R8 loop verbatim)
// + FUSED split-K merge epilogue (last-arriving split block per query tile
// normalizes, applies W4/b4/gamma/residual, writes out).
// QK computed transposed (A=f-ext, B=g-ext); post-exp2 P registers are the
// PV A-frag under the hT key permutation (verified R8).
// launch_bounds(128,4): R8-proven 44 VGPR, NO min-waves>=8 hint (R9/R10
// showed any such hint forces allocation below demand -> scratch spill).
// TLP from the grid: QT*KS = 4608 blocks = 36 waves/CU available.
// ---------------------------------------------------------------------------
__global__ __launch_bounds__(128, 4) void attn_kernel(
    const short* __restrict__ fx, const short* __restrict__ gx,
    const short* __restrict__ hT,
    float* __restrict__ l_acc, float* __restrict__ o_acc,
    int* __restrict__ cnt,
    const float* __restrict__ x,
    const float* __restrict__ W4, const float* __restrict__ b4,
    const float* __restrict__ gamma, float* __restrict__ out)
{
    __shared__ float red[32 * 33];            // epilogue-only, 4224 B
    __shared__ int lastS;

    const int tid  = threadIdx.x;
    const int wave = tid >> 6;
    const int lane = tid & 63;
    const int col  = lane & 15;
    const int quad = lane >> 4;

    const int blk = blockIdx.x;
    const int qt  = blk % QT;                 // query tile 0..575
    const int ks  = blk / QT;                 // key split 0..7
    const int b   = qt / (QT / BATCH);        // batch
    const int qbase   = (qt % (QT / BATCH)) * 32;
    const int rowbase = b * NTOK + qbase;

    // persistent B-operands for QK: g-ext for 2 query sub-tiles
    const bf16x8 agA = *(const bf16x8*)(gx + (size_t)(rowbase + col) * 32 + quad * 8);
    const bf16x8 agB = *(const bf16x8*)(gx + (size_t)(rowbase + 16 + col) * 32 + quad * 8);

    f32x4 oA0 = {0.f,0.f,0.f,0.f}, oA1 = {0.f,0.f,0.f,0.f};
    f32x4 oB0 = {0.f,0.f,0.f,0.f}, oB1 = {0.f,0.f,0.f,0.f};
    float lA = 0.f, lB = 0.f;
    const f32x4 zero4 = {0.f,0.f,0.f,0.f};

    const int kstart = ks * KEYS_PER_BLOCK + wave * KEYS_PER_WAVE;
    const short* fbase = fx + ((size_t)b * NTOK + kstart) * 32;
    const short* hp0 = hT + ((size_t)(b * 32 + col)) * NTOK + kstart;       // v=col
    const short* hp1 = hT + ((size_t)(b * 32 + 16 + col)) * NTOK + kstart;  // v=16+col

    // preload tile 0
    bf16x8 fa0 = *(const bf16x8*)(fbase + (size_t)col * 32 + quad * 8);        // keys 0-15
    bf16x8 fa1 = *(const bf16x8*)(fbase + (size_t)(16 + col) * 32 + quad * 8); // keys 16-31
    bf16x8 hb0 = *(const bf16x8*)(hp0 + quad * 8);
    bf16x8 hb1 = *(const bf16x8*)(hp1 + quad * 8);

    union PU { int i[4]; bf16x8 v; };

    for (int t = 0; t < NKT; ++t) {
        // QK transposed: lane holds S[q=col][k=quad*4+r]
        f32x4 t00 = __builtin_amdgcn_mfma_f32_16x16x32_bf16(fa0, agA, zero4, 0, 0, 0);
        f32x4 t01 = __builtin_amdgcn_mfma_f32_16x16x32_bf16(fa1, agA, zero4, 0, 0, 0);
        f32x4 t10 = __builtin_amdgcn_mfma_f32_16x16x32_bf16(fa0, agB, zero4, 0, 0, 0);
        f32x4 t11 = __builtin_amdgcn_mfma_f32_16x16x32_bf16(fa1, agB, zero4, 0, 0, 0);

        // prefetch tile t+1 (clamped; discarded on last iter)
        const int kn = (t + 1 < NKT) ? (t + 1) * KT : 0;
        bf16x8 nf0 = *(const bf16x8*)(fbase + (size_t)(kn + col) * 32 + quad * 8);
        bf16x8 nf1 = *(const bf16x8*)(fbase + (size_t)(kn + 16 + col) * 32 + quad * 8);
        bf16x8 nh0 = *(const bf16x8*)(hp0 + kn + quad * 8);
        bf16x8 nh1 = *(const bf16x8*)(hp1 + kn + quad * 8);

        // exp2 + round-to-bf16 + pack: P registers ARE the PV A-frag
        PU pA, pB;
        {
            float e0 = __builtin_amdgcn_exp2f(t00[0]), e1 = __builtin_amdgcn_exp2f(t00[1]);
            float e2 = __builtin_amdgcn_exp2f(t00[2]), e3 = __builtin_amdgcn_exp2f(t00[3]);
            float e4 = __builtin_amdgcn_exp2f(t01[0]), e5 = __builtin_amdgcn_exp2f(t01[1]);
            float e6 = __builtin_amdgcn_exp2f(t01[2]), e7 = __builtin_amdgcn_exp2f(t01[3]);
            lA += (e0 + e1) + (e2 + e3) + (e4 + e5) + (e6 + e7);
            pA.i[0] = (int)__builtin_amdgcn_perm((unsigned)__float_as_int(e1) + 0x8000u,
                                                 (unsigned)__float_as_int(e0) + 0x8000u, 0x07060302u);
            pA.i[1] = (int)__builtin_amdgcn_perm((unsigned)__float_as_int(e3) + 0x8000u,
                                                 (unsigned)__float_as_int(e2) + 0x8000u, 0x07060302u);
            pA.i[2] = (int)__builtin_amdgcn_perm((unsigned)__float_as_int(e5) + 0x8000u,
                                                 (unsigned)__float_as_int(e4) + 0x8000u, 0x07060302u);
            pA.i[3] = (int)__builtin_amdgcn_perm((unsigned)__float_as_int(e7) + 0x8000u,
                                                 (unsigned)__float_as_int(e6) + 0x8000u, 0x07060302u);
        }
        {
            float e0 = __builtin_amdgcn_exp2f(t10[0]), e1 = __builtin_amdgcn_exp2f(t10[1]);
            float e2 = __builtin_amdgcn_exp2f(t10[2]), e3 = __builtin_amdgcn_exp2f(t10[3]);
            float e4 = __builtin_amdgcn_exp2f(t11[0]), e5 = __builtin_amdgcn_exp2f(t11[1]);
            float e6 = __builtin_amdgcn_exp2f(t11[2]), e7 = __builtin_amdgcn_exp2f(t11[3]);
            lB += (e0 + e1) + (e2 + e3) + (e4 + e5) + (e6 + e7);
            pB.i[0] = (int)__builtin_amdgcn_perm((unsigned)__float_as_int(e1) + 0x8000u,
                                                 (unsigned)__float_as_int(e0) + 0x8000u, 0x07060302u);
            pB.i[1] = (int)__builtin_amdgcn_perm((unsigned)__float_as_int(e3) + 0x8000u,
                                                 (unsigned)__float_as_int(e2) + 0x8000u, 0x07060302u);
            pB.i[2] = (int)__builtin_amdgcn_perm((unsigned)__float_as_int(e5) + 0x8000u,
                                                 (unsigned)__float_as_int(e4) + 0x8000u, 0x07060302u);
            pB.i[3] = (int)__builtin_amdgcn_perm((unsigned)__float_as_int(e7) + 0x8000u,
                                                 (unsigned)__float_as_int(e6) + 0x8000u, 0x07060302u);
        }

        // PV: A = packed P (direct), B = permuted hT frags
        oA0 = __builtin_amdgcn_mfma_f32_16x16x32_bf16(pA.v, hb0, oA0, 0, 0, 0);
        oA1 = __builtin_amdgcn_mfma_f32_16x16x32_bf16(pA.v, hb1, oA1, 0, 0, 0);
        oB0 = __builtin_amdgcn_mfma_f32_16x16x32_bf16(pB.v, hb0, oB0, 0, 0, 0);
        oB1 = __builtin_amdgcn_mfma_f32_16x16x32_bf16(pB.v, hb1, oB1, 0, 0, 0);

        fa0 = nf0; fa1 = nf1; hb0 = nh0; hb1 = nh1;
    }

    // l: reduce across quads (lanes col, col+16, col+32, col+48 share q=col)
    lA += __shfl_xor(lA, 16); lA += __shfl_xor(lA, 32);
    lB += __shfl_xor(lB, 16); lB += __shfl_xor(lB, 32);

    // cross-wave merge: wave1 stores to red, wave0 combines + global atomics.
    if (wave == 1) {
        #pragma unroll
        for (int r = 0; r < 4; ++r) {
            red[(quad * 4 + r) * 33 + col]           = oA0[r];
            red[(quad * 4 + r) * 33 + 16 + col]      = oA1[r];
            red[(16 + quad * 4 + r) * 33 + col]      = oB0[r];
            red[(16 + quad * 4 + r) * 33 + 16 + col] = oB1[r];
        }
        if (quad == 0) {
            red[col * 33 + 32]        = lA;
            red[(16 + col) * 33 + 32] = lB;
        }
    }
    __syncthreads();
    if (wave == 0) {
        #pragma unroll
        for (int r = 0; r < 4; ++r) {
            int qA = quad * 4 + r, qB = 16 + quad * 4 + r;
            atomicAdd(&o_acc[(size_t)(rowbase + qA) * 32 + col],      oA0[r] + red[qA * 33 + col]);
            atomicAdd(&o_acc[(size_t)(rowbase + qA) * 32 + 16 + col], oA1[r] + red[qA * 33 + 16 + col]);
            atomicAdd(&o_acc[(size_t)(rowbase + qB) * 32 + col],      oB0[r] + red[qB * 33 + col]);
            atomicAdd(&o_acc[(size_t)(rowbase + qB) * 32 + 16 + col], oB1[r] + red[qB * 33 + 16 + col]);
        }
        if (quad == 0) {
            atomicAdd(&l_acc[rowbase + col],      lA + red[col * 33 + 32]);
            atomicAdd(&l_acc[rowbase + 16 + col], lB + red[(16 + col) * 33 + 32]);
        }
    }

    // ---- fused merge epilogue: last split block per qt does the output ----
    if (tid == 0) {
        __threadfence();   // make this block's atomics visible before signal
        int old = __hip_atomic_fetch_add(&cnt[qt], 1, __ATOMIC_ACQ_REL,
                                         __HIP_MEMORY_SCOPE_AGENT);
        lastS = (old == KS - 1) ? 1 : 0;
    }
    __syncthreads();
    if (lastS) {
        // reload red with finished o_acc/l_acc (agent-scope loads: L1-safe)
        for (int i = tid; i < 32 * 33; i += 128) {
            int q = i / 33, vv = i - q * 33;
            const float* src = (vv == 32)
                ? &l_acc[rowbase + q]
                : &o_acc[(size_t)(rowbase + q) * 32 + vv];
            red[i] = __hip_atomic_load(src, __ATOMIC_RELAXED, __HIP_MEMORY_SCOPE_AGENT);
        }
        __syncthreads();

        const int c  = tid & 63;
        const int qh = (tid >> 6) * 16;       // 0 or 16
        float accq[16];
        #pragma unroll
        for (int i = 0; i < 16; ++i) accq[i] = 0.f;
        #pragma unroll
        for (int vc = 0; vc < 4; ++vc) {
            float w4v[8];
            #pragma unroll
            for (int j = 0; j < 8; ++j) w4v[j] = W4[(vc * 8 + j) * 64 + c];
            #pragma unroll
            for (int qq = 0; qq < 16; ++qq) {
                #pragma unroll
                for (int j = 0; j < 8; ++j)
                    accq[qq] += red[(qh + qq) * 33 + vc * 8 + j] * w4v[j];
            }
        }
        float gm  = gamma[0];
        float b4c = b4[c];
        #pragma unroll
        for (int qq = 0; qq < 16; ++qq) {
            int row = rowbase + qh + qq;
            float invL = 1.f / red[(qh + qq) * 33 + 32];
            out[(size_t)row * 64 + c] = gm * (accq[qq] * invL + b4c)
                                      + x[(size_t)row * 64 + c];
        }
    }
}

// ---------------------------------------------------------------------------
extern "C" void kernel_launch(void* const* d_in, const int* in_sizes, int n_in,
                              void* d_out, int out_size, void* d_ws, size_t ws_size,
                              hipStream_t stream) {
    const float* x     = (const float*)d_in[0];
    const float* W1    = (const float*)d_in[1];
    const float* b1    = (const float*)d_in[2];
    const float* W2    = (const float*)d_in[3];
    const float* b2    = (const float*)d_in[4];
    const float* W3    = (const float*)d_in[5];
    const float* b3    = (const float*)d_in[6];
    const float* W4    = (const float*)d_in[7];
    const float* b4    = (const float*)d_in[8];
    const float* gamma = (const float*)d_in[9];
    float* out = (float*)d_out;

    // Workspace: fx/gx/hT bf16 (1.18 MB each) + l_acc + o_acc + cnt ≈ 6 MB
    short* fx    = (short*)d_ws;                       // 589824 shorts
    short* gx    = fx + (size_t)ROWS * 32;             // 589824 shorts
    short* hT    = gx + (size_t)ROWS * 32;             // 589824 shorts
    float* l_acc = (float*)(hT + (size_t)ROWS * 32);   // 18432 floats
    float* o_acc = l_acc + ROWS;                       // 589824 floats
    int*   cnt   = (int*)(o_acc + (size_t)ROWS * 32);  // 576 ints

    // proj (+ zeroing of l_acc/o_acc/cnt): 576 blocks x 512 threads
    proj_kernel<<<ROWS / PB, 512, 0, stream>>>(
        x, W1, b1, W2, b2, W3, b3, fx, gx, hT, (float4*)l_acc);

    // attention + fused merge: 576 query-tiles x 8 key-splits = 4608 blocks
    attn_kernel<<<QT * KS, 128, 0, stream>>>(
        fx, gx, hT, l_acc, o_acc, cnt, x, W4, b4, gamma, out);
}

// Round 12
// 156.068 us; speedup vs baseline: 2.1767x; 2.1767x over previous
//
#include <hip/hip_runtime.h>
#include <hip/hip_bf16.h>

// All reference dtypes are float32 (verified R3): inputs const float*, output float*.

#define BATCH 2
#define NTOK 9216        // 96*96
#define CCH 64
#define DV 32
#define KS 8                          // key splits (per block; x2 waves -> eff 16)
#define KEYS_PER_BLOCK (NTOK / KS)    // 1152
#define KEYS_PER_WAVE (KEYS_PER_BLOCK / 2)  // 576 (per wave)
#define KT 32                         // keys per MFMA tile
#define NKT (KEYS_PER_WAVE / KT)      // 18 tiles per wave
#define ROWS (BATCH * NTOK)           // 18432
#define QT (ROWS / 32)                // 576 query tiles (32 q per block)
#define LOG2E 1.44269504088896340736f
#define PB 32                         // proj rows per block
#define ZTOT 152064                   // float4s to zero: l_acc+o_acc

typedef __attribute__((ext_vector_type(8))) short bf16x8;   // 8 bf16 (4 VGPRs)
typedef __attribute__((ext_vector_type(4))) float f32x4;    // MFMA C/D

__device__ __forceinline__ short f2bf(float x) {
    __hip_bfloat16 h = __float2bfloat16(x);   // RNE
    return *(short*)&h;
}
__device__ __forceinline__ float bf2f(short s) {
    unsigned u = ((unsigned)(unsigned short)s) << 16;
    return *(float*)&u;
}

// ---------------------------------------------------------------------------
// Kernel 1: projections -> MFMA-ready bf16 operands + zeroing of l/o_acc.
//  gx[row][32]: [g_hi(8) | g_lo(8) | g_hi(8) | 0]   (g pre-scaled by log2e)
//  fx[key][32]: [f_hi(8) | f_hi(8) | f_lo(8) | 0]
//  hT[b][v][k_pv]: transposed H with keys permuted within each 32-key tile:
//   np(ni) = ((ni&15)>>2)*8 + (ni&3) + ((ni>>4)&1)*4  — makes post-exp2 P
//   registers directly usable as the PV A-frag (verified R8).
// ---------------------------------------------------------------------------
__global__ __launch_bounds__(512) void proj_kernel(
    const float* __restrict__ x,
    const float* __restrict__ W1, const float* __restrict__ b1,
    const float* __restrict__ W2, const float* __restrict__ b2,
    const float* __restrict__ W3, const float* __restrict__ b3,
    short* __restrict__ fx, short* __restrict__ gx, short* __restrict__ hT,
    float4* __restrict__ zbase)
{
    __shared__ float xS[PB][CCH];        // 8 KB
    __shared__ short fgS[2][PB][32];     // 4 KB staging for fx, gx
    __shared__ short hS[32][PB + 2];     // 2.1 KB staging for hT

    const int tid = threadIdx.x;
    const int r0  = blockIdx.x * PB;     // 32-row tile, batch-aligned

    // zero l_acc + o_acc: one float4 per thread, grid covers ZTOT
    {
        int zi = blockIdx.x * 512 + tid;
        if (zi < ZTOT) zbase[zi] = make_float4(0.f, 0.f, 0.f, 0.f);
    }

    // cooperative x load: 512 threads x float4 = 32 rows x 64 floats
    ((float4*)xS)[tid] = ((const float4*)(x + (size_t)r0 * CCH))[tid];
    __syncthreads();

    // phase 1: f (tid<256) / g (tid>=256) — wave-uniform split
    {
        const int half = tid >> 8;            // 0: f, 1: g
        const int rr   = (tid & 255) >> 3;    // 0..31
        const int c    = tid & 7;             // 0..7
        const float* xr = xS[rr];
        if (half == 0) {
            float acc = b1[c];
            #pragma unroll
            for (int k = 0; k < CCH; ++k) acc += xr[k] * W1[k * 8 + c];
            short hi = f2bf(acc);
            short lo = f2bf(acc - bf2f(hi));
            fgS[0][rr][c] = hi; fgS[0][rr][c + 8] = hi;
            fgS[0][rr][c + 16] = lo; fgS[0][rr][c + 24] = 0;
        } else {
            float acc = b2[c];
            #pragma unroll
            for (int k = 0; k < CCH; ++k) acc += xr[k] * W2[k * 8 + c];
            acc *= LOG2E;                 // fold log2(e) for exp2 inner loop
            short hi = f2bf(acc);
            short lo = f2bf(acc - bf2f(hi));
            fgS[1][rr][c] = hi; fgS[1][rr][c + 8] = lo;
            fgS[1][rr][c + 16] = hi; fgS[1][rr][c + 24] = 0;
        }
    }
    // phase 2: h — thread (c = tid&31, rbase = tid>>5) covers rows rbase, rbase+16
    {
        const int c = tid & 31;
        const int rbase = tid >> 5;
        #pragma unroll
        for (int s = 0; s < 2; ++s) {
            int rr = rbase + s * 16;
            float acc = b3[c];
            #pragma unroll
            for (int k = 0; k < CCH; ++k) acc += xS[rr][k] * W3[k * 32 + c];
            int np = ((rr & 15) >> 2) * 8 + (rr & 3) + ((rr >> 4) & 1) * 4;
            hS[c][np] = f2bf(acc);
        }
    }
    __syncthreads();

    // coalesced write-out (dwords)
    ((int*)(fx + (size_t)r0 * 32))[tid] = ((const int*)fgS[0])[tid];
    ((int*)(gx + (size_t)r0 * 32))[tid] = ((const int*)fgS[1])[tid];
    {
        const int b  = r0 / NTOK;
        const int n0 = r0 - b * NTOK;
        const int c  = tid >> 4;
        const int d  = tid & 15;
        ((int*)(hT + (size_t)(b * 32 + c) * NTOK + n0))[d] = ((const int*)&hS[c][0])[d];
    }
}

// ---------------------------------------------------------------------------
// Kernel 2: MFMA flash attention with ZERO in-loop LDS (R8 loop verbatim).
// QK computed transposed (A=f-ext, B=g-ext): lane holds S[q=col][k=quad*4+r].
// After exp2, each lane's 8 P values are EXACTLY the PV A-frag under the hT
// key permutation — no LDS round-trip. l per-lane, shfl-reduced.
// Block = 2 waves over the SAME 32 queries, each wave half the key split.
// TLP from the grid: QT*KS = 4608 blocks = 36 waves/CU offered; 44 VGPR and
// 4.6 KB LDS both allow 16 blocks/CU -> 8 waves/SIMD resident.
// launch_bounds(128,4) ONLY (R9/R10: any min-waves>=8 hint forces allocation
// below the ~44-reg demand -> scratch spill; R11 verified (128,4)+KS=8 = 44
// VGPR, no spill). NO fused epilogue (R11: agent-scope acquire/release =
// L2 writeback/invalidate per block on non-coherent-XCD gfx950 -> 3x stall).
// ---------------------------------------------------------------------------
__global__ __launch_bounds__(128, 4) void attn_kernel(
    const short* __restrict__ fx, const short* __restrict__ gx,
    const short* __restrict__ hT,
    float* __restrict__ l_acc, float* __restrict__ o_acc)
{
    __shared__ float red[32 * 33];            // epilogue-only, 4224 B

    const int tid  = threadIdx.x;
    const int wave = tid >> 6;
    const int lane = tid & 63;
    const int col  = lane & 15;
    const int quad = lane >> 4;

    const int blk = blockIdx.x;
    const int qt  = blk % QT;                 // query tile 0..575
    const int ks  = blk / QT;                 // key split 0..7
    const int b   = qt / (QT / BATCH);        // batch
    const int qbase   = (qt % (QT / BATCH)) * 32;
    const int rowbase = b * NTOK + qbase;

    // persistent B-operands for QK: g-ext for 2 query sub-tiles
    const bf16x8 agA = *(const bf16x8*)(gx + (size_t)(rowbase + col) * 32 + quad * 8);
    const bf16x8 agB = *(const bf16x8*)(gx + (size_t)(rowbase + 16 + col) * 32 + quad * 8);

    f32x4 oA0 = {0.f,0.f,0.f,0.f}, oA1 = {0.f,0.f,0.f,0.f};
    f32x4 oB0 = {0.f,0.f,0.f,0.f}, oB1 = {0.f,0.f,0.f,0.f};
    float lA = 0.f, lB = 0.f;
    const f32x4 zero4 = {0.f,0.f,0.f,0.f};

    const int kstart = ks * KEYS_PER_BLOCK + wave * KEYS_PER_WAVE;
    const short* fbase = fx + ((size_t)b * NTOK + kstart) * 32;
    const short* hp0 = hT + ((size_t)(b * 32 + col)) * NTOK + kstart;       // v=col
    const short* hp1 = hT + ((size_t)(b * 32 + 16 + col)) * NTOK + kstart;  // v=16+col

    // preload tile 0
    bf16x8 fa0 = *(const bf16x8*)(fbase + (size_t)col * 32 + quad * 8);        // keys 0-15
    bf16x8 fa1 = *(const bf16x8*)(fbase + (size_t)(16 + col) * 32 + quad * 8); // keys 16-31
    bf16x8 hb0 = *(const bf16x8*)(hp0 + quad * 8);
    bf16x8 hb1 = *(const bf16x8*)(hp1 + quad * 8);

    union PU { int i[4]; bf16x8 v; };

    for (int t = 0; t < NKT; ++t) {
        // QK transposed: lane holds S[q=col][k=quad*4+r]
        f32x4 t00 = __builtin_amdgcn_mfma_f32_16x16x32_bf16(fa0, agA, zero4, 0, 0, 0);
        f32x4 t01 = __builtin_amdgcn_mfma_f32_16x16x32_bf16(fa1, agA, zero4, 0, 0, 0);
        f32x4 t10 = __builtin_amdgcn_mfma_f32_16x16x32_bf16(fa0, agB, zero4, 0, 0, 0);
        f32x4 t11 = __builtin_amdgcn_mfma_f32_16x16x32_bf16(fa1, agB, zero4, 0, 0, 0);

        // prefetch tile t+1 (clamped; discarded on last iter)
        const int kn = (t + 1 < NKT) ? (t + 1) * KT : 0;
        bf16x8 nf0 = *(const bf16x8*)(fbase + (size_t)(kn + col) * 32 + quad * 8);
        bf16x8 nf1 = *(const bf16x8*)(fbase + (size_t)(kn + 16 + col) * 32 + quad * 8);
        bf16x8 nh0 = *(const bf16x8*)(hp0 + kn + quad * 8);
        bf16x8 nh1 = *(const bf16x8*)(hp1 + kn + quad * 8);

        // exp2 + round-to-bf16 + pack: P registers ARE the PV A-frag
        PU pA, pB;
        {
            float e0 = __builtin_amdgcn_exp2f(t00[0]), e1 = __builtin_amdgcn_exp2f(t00[1]);
            float e2 = __builtin_amdgcn_exp2f(t00[2]), e3 = __builtin_amdgcn_exp2f(t00[3]);
            float e4 = __builtin_amdgcn_exp2f(t01[0]), e5 = __builtin_amdgcn_exp2f(t01[1]);
            float e6 = __builtin_amdgcn_exp2f(t01[2]), e7 = __builtin_amdgcn_exp2f(t01[3]);
            lA += (e0 + e1) + (e2 + e3) + (e4 + e5) + (e6 + e7);
            pA.i[0] = (int)__builtin_amdgcn_perm((unsigned)__float_as_int(e1) + 0x8000u,
                                                 (unsigned)__float_as_int(e0) + 0x8000u, 0x07060302u);
            pA.i[1] = (int)__builtin_amdgcn_perm((unsigned)__float_as_int(e3) + 0x8000u,
                                                 (unsigned)__float_as_int(e2) + 0x8000u, 0x07060302u);
            pA.i[2] = (int)__builtin_amdgcn_perm((unsigned)__float_as_int(e5) + 0x8000u,
                                                 (unsigned)__float_as_int(e4) + 0x8000u, 0x07060302u);
            pA.i[3] = (int)__builtin_amdgcn_perm((unsigned)__float_as_int(e7) + 0x8000u,
                                                 (unsigned)__float_as_int(e6) + 0x8000u, 0x07060302u);
        }
        {
            float e0 = __builtin_amdgcn_exp2f(t10[0]), e1 = __builtin_amdgcn_exp2f(t10[1]);
            float e2 = __builtin_amdgcn_exp2f(t10[2]), e3 = __builtin_amdgcn_exp2f(t10[3]);
            float e4 = __builtin_amdgcn_exp2f(t11[0]), e5 = __builtin_amdgcn_exp2f(t11[1]);
            float e6 = __builtin_amdgcn_exp2f(t11[2]), e7 = __builtin_amdgcn_exp2f(t11[3]);
            lB += (e0 + e1) + (e2 + e3) + (e4 + e5) + (e6 + e7);
            pB.i[0] = (int)__builtin_amdgcn_perm((unsigned)__float_as_int(e1) + 0x8000u,
                                                 (unsigned)__float_as_int(e0) + 0x8000u, 0x07060302u);
            pB.i[1] = (int)__builtin_amdgcn_perm((unsigned)__float_as_int(e3) + 0x8000u,
                                                 (unsigned)__float_as_int(e2) + 0x8000u, 0x07060302u);
            pB.i[2] = (int)__builtin_amdgcn_perm((unsigned)__float_as_int(e5) + 0x8000u,
                                                 (unsigned)__float_as_int(e4) + 0x8000u, 0x07060302u);
            pB.i[3] = (int)__builtin_amdgcn_perm((unsigned)__float_as_int(e7) + 0x8000u,
                                                 (unsigned)__float_as_int(e6) + 0x8000u, 0x07060302u);
        }

        // PV: A = packed P (direct), B = permuted hT frags
        oA0 = __builtin_amdgcn_mfma_f32_16x16x32_bf16(pA.v, hb0, oA0, 0, 0, 0);
        oA1 = __builtin_amdgcn_mfma_f32_16x16x32_bf16(pA.v, hb1, oA1, 0, 0, 0);
        oB0 = __builtin_amdgcn_mfma_f32_16x16x32_bf16(pB.v, hb0, oB0, 0, 0, 0);
        oB1 = __builtin_amdgcn_mfma_f32_16x16x32_bf16(pB.v, hb1, oB1, 0, 0, 0);

        fa0 = nf0; fa1 = nf1; hb0 = nh0; hb1 = nh1;
    }

    // l: reduce across quads (lanes col, col+16, col+32, col+48 share q=col)
    lA += __shfl_xor(lA, 16); lA += __shfl_xor(lA, 32);
    lB += __shfl_xor(lB, 16); lB += __shfl_xor(lB, 32);

    // cross-wave merge: wave1 stores to red, wave0 combines + global atomics.
    // O layout: lane holds O[q=quad*4+r][v=col] (oX0) / [v=16+col] (oX1).
    if (wave == 1) {
        #pragma unroll
        for (int r = 0; r < 4; ++r) {
            red[(quad * 4 + r) * 33 + col]           = oA0[r];
            red[(quad * 4 + r) * 33 + 16 + col]      = oA1[r];
            red[(16 + quad * 4 + r) * 33 + col]      = oB0[r];
            red[(16 + quad * 4 + r) * 33 + 16 + col] = oB1[r];
        }
        if (quad == 0) {
            red[col * 33 + 32]        = lA;
            red[(16 + col) * 33 + 32] = lB;
        }
    }
    __syncthreads();
    if (wave == 0) {
        #pragma unroll
        for (int r = 0; r < 4; ++r) {
            int qA = quad * 4 + r, qB = 16 + quad * 4 + r;
            atomicAdd(&o_acc[(size_t)(rowbase + qA) * 32 + col],      oA0[r] + red[qA * 33 + col]);
            atomicAdd(&o_acc[(size_t)(rowbase + qA) * 32 + 16 + col], oA1[r] + red[qA * 33 + 16 + col]);
            atomicAdd(&o_acc[(size_t)(rowbase + qB) * 32 + col],      oB0[r] + red[qB * 33 + col]);
            atomicAdd(&o_acc[(size_t)(rowbase + qB) * 32 + 16 + col], oB1[r] + red[qB * 33 + 16 + col]);
        }
        if (quad == 0) {
            atomicAdd(&l_acc[rowbase + col],      lA + red[col * 33 + 32]);
            atomicAdd(&l_acc[rowbase + 16 + col], lB + red[(16 + col) * 33 + 32]);
        }
    }
}

// ---------------------------------------------------------------------------
// Kernel 3: normalize + output projection + residual (fp32 weights).
// One wave per query: o[k] = o_acc/l ; out = gamma*(o@W4 + b4) + x
// ---------------------------------------------------------------------------
__global__ __launch_bounds__(256) void merge_kernel(
    const float* __restrict__ l_acc, const float* __restrict__ o_acc,
    const float* __restrict__ x,
    const float* __restrict__ W4, const float* __restrict__ b4,
    const float* __restrict__ gamma, float* __restrict__ out)
{
    __shared__ float oS[4][DV];
    int wave = threadIdx.x >> 6;
    int lane = threadIdx.x & 63;
    int row  = blockIdx.x * 4 + wave;     // < 18432 exactly

    float invL = 1.f / l_acc[row];
    if (lane < DV) {
        oS[wave][lane] = o_acc[(size_t)row * DV + lane] * invL;
    }
    __syncthreads();

    float dot = b4[lane];
    #pragma unroll
    for (int k = 0; k < DV; ++k) dot += oS[wave][k] * W4[k * 64 + lane];
    float gm  = gamma[0];
    float res = x[(size_t)row * 64 + lane];
    out[(size_t)row * 64 + lane] = gm * dot + res;
}

// ---------------------------------------------------------------------------
extern "C" void kernel_launch(void* const* d_in, const int* in_sizes, int n_in,
                              void* d_out, int out_size, void* d_ws, size_t ws_size,
                              hipStream_t stream) {
    const float* x     = (const float*)d_in[0];
    const float* W1    = (const float*)d_in[1];
    const float* b1    = (const float*)d_in[2];
    const float* W2    = (const float*)d_in[3];
    const float* b2    = (const float*)d_in[4];
    const float* W3    = (const float*)d_in[5];
    const float* b3    = (const float*)d_in[6];
    const float* W4    = (const float*)d_in[7];
    const float* b4    = (const float*)d_in[8];
    const float* gamma = (const float*)d_in[9];
    float* out = (float*)d_out;

    // Workspace: fx/gx/hT bf16 (1.18 MB each) + l_acc + o_acc = 5.97 MB total
    short* fx    = (short*)d_ws;                       // 589824 shorts
    short* gx    = fx + (size_t)ROWS * 32;             // 589824 shorts
    short* hT    = gx + (size_t)ROWS * 32;             // 589824 shorts
    float* l_acc = (float*)(hT + (size_t)ROWS * 32);   // 18432 floats
    float* o_acc = l_acc + ROWS;                       // 589824 floats

    // proj (+ zeroing of l_acc/o_acc): 576 blocks x 512 threads
    proj_kernel<<<ROWS / PB, 512, 0, stream>>>(
        x, W1, b1, W2, b2, W3, b3, fx, gx, hT, (float4*)l_acc);

    // attention: 576 query-tiles x 8 key-splits = 4608 blocks x 2 waves
    attn_kernel<<<QT * KS, 128, 0, stream>>>(fx, gx, hT, l_acc, o_acc);

    // merge: 18432 queries / 4 waves per block
    merge_kernel<<<ROWS / 4, 256, 0, stream>>>(l_acc, o_acc, x, W4, b4, gamma, out);
}

// Round 13
// 140.254 us; speedup vs baseline: 2.4222x; 1.1128x over previous
//
#include <hip/hip_runtime.h>
#include <hip/hip_bf16.h>

// All reference dtypes are float32 (verified R3): inputs const float*, output float*.

#define BATCH 2
#define NTOK 9216        // 96*96
#define CCH 64
#define DV 32
#define KS 8                          // key splits (per block; x2 waves -> eff 16)
#define KEYS_PER_BLOCK (NTOK / KS)    // 1152
#define KEYS_PER_WAVE (KEYS_PER_BLOCK / 2)  // 576 (per wave)
#define KT 32                         // keys per MFMA tile
#define NKT (KEYS_PER_WAVE / KT)      // 18 tiles per wave
#define ROWS (BATCH * NTOK)           // 18432
#define QT (ROWS / 32)                // 576 query tiles (32 q per block)
#define NKTILE (NTOK / 32)            // 288 key tiles per batch
#define LOG2E 1.44269504088896340736f
#define PB 32                         // proj rows per block
#define ZTOT 152064                   // float4s to zero: l_acc+o_acc

typedef __attribute__((ext_vector_type(8))) short bf16x8;   // 8 bf16 (4 VGPRs)
typedef __attribute__((ext_vector_type(4))) float f32x4;    // MFMA C/D

__device__ __forceinline__ short f2bf(float x) {
    __hip_bfloat16 h = __float2bfloat16(x);   // RNE
    return *(short*)&h;
}
__device__ __forceinline__ float bf2f(short s) {
    unsigned u = ((unsigned)(unsigned short)s) << 16;
    return *(float*)&u;
}

// ---------------------------------------------------------------------------
// Kernel 1: projections -> MFMA-ready bf16 operands + zeroing of l/o_acc.
//  gx[row][32]: [g_hi(8) | g_lo(8) | g_hi(8) | 0]   (g pre-scaled by log2e)
//  fx[key][32]: [f_hi(8) | f_hi(8) | f_lo(8) | 0]
//  hTi[b][key_tile][v][k']: TILE-BLOCKED transposed H — each 32-key tile's
//   32v x 32k bf16 block is a contiguous 2 KB region (R13: kills the 18 KB
//   row-stride gather that serialized on 2 L2 channels, the R6-R12 70 µs
//   floor). k' permutation np(ni) = ((ni&15)>>2)*8 + (ni&3) + ((ni>>4)&1)*4
//   makes post-exp2 P registers directly usable as the PV A-frag (R8).
// ---------------------------------------------------------------------------
__global__ __launch_bounds__(512) void proj_kernel(
    const float* __restrict__ x,
    const float* __restrict__ W1, const float* __restrict__ b1,
    const float* __restrict__ W2, const float* __restrict__ b2,
    const float* __restrict__ W3, const float* __restrict__ b3,
    short* __restrict__ fx, short* __restrict__ gx, short* __restrict__ hTi,
    float4* __restrict__ zbase)
{
    __shared__ float xS[PB][CCH];        // 8 KB
    __shared__ short fgS[2][PB][32];     // 4 KB staging for fx, gx
    __shared__ short hS[32][PB + 2];     // 2.1 KB staging for hTi

    const int tid = threadIdx.x;
    const int r0  = blockIdx.x * PB;     // 32-row tile == one key tile

    // zero l_acc + o_acc: one float4 per thread, grid covers ZTOT
    {
        int zi = blockIdx.x * 512 + tid;
        if (zi < ZTOT) zbase[zi] = make_float4(0.f, 0.f, 0.f, 0.f);
    }

    // cooperative x load: 512 threads x float4 = 32 rows x 64 floats
    ((float4*)xS)[tid] = ((const float4*)(x + (size_t)r0 * CCH))[tid];
    __syncthreads();

    // phase 1: f (tid<256) / g (tid>=256) — wave-uniform split
    {
        const int half = tid >> 8;            // 0: f, 1: g
        const int rr   = (tid & 255) >> 3;    // 0..31
        const int c    = tid & 7;             // 0..7
        const float* xr = xS[rr];
        if (half == 0) {
            float acc = b1[c];
            #pragma unroll
            for (int k = 0; k < CCH; ++k) acc += xr[k] * W1[k * 8 + c];
            short hi = f2bf(acc);
            short lo = f2bf(acc - bf2f(hi));
            fgS[0][rr][c] = hi; fgS[0][rr][c + 8] = hi;
            fgS[0][rr][c + 16] = lo; fgS[0][rr][c + 24] = 0;
        } else {
            float acc = b2[c];
            #pragma unroll
            for (int k = 0; k < CCH; ++k) acc += xr[k] * W2[k * 8 + c];
            acc *= LOG2E;                 // fold log2(e) for exp2 inner loop
            short hi = f2bf(acc);
            short lo = f2bf(acc - bf2f(hi));
            fgS[1][rr][c] = hi; fgS[1][rr][c + 8] = lo;
            fgS[1][rr][c + 16] = hi; fgS[1][rr][c + 24] = 0;
        }
    }
    // phase 2: h — thread (c = tid&31, rbase = tid>>5) covers rows rbase, rbase+16
    {
        const int c = tid & 31;
        const int rbase = tid >> 5;
        #pragma unroll
        for (int s = 0; s < 2; ++s) {
            int rr = rbase + s * 16;
            float acc = b3[c];
            #pragma unroll
            for (int k = 0; k < CCH; ++k) acc += xS[rr][k] * W3[k * 32 + c];
            int np = ((rr & 15) >> 2) * 8 + (rr & 3) + ((rr >> 4) & 1) * 4;
            hS[c][np] = f2bf(acc);
        }
    }
    __syncthreads();

    // coalesced write-out (dwords)
    ((int*)(fx + (size_t)r0 * 32))[tid] = ((const int*)fgS[0])[tid];
    ((int*)(gx + (size_t)r0 * 32))[tid] = ((const int*)fgS[1])[tid];
    {
        const int b  = r0 / NTOK;
        const int n0 = r0 - b * NTOK;
        const int kt = n0 >> 5;               // key tile within batch
        const int c  = tid >> 4;              // v = 0..31
        const int d  = tid & 15;              // dword within 64B v-row
        ((int*)(hTi + ((size_t)(b * NKTILE + kt)) * 1024))[c * 16 + d] =
            ((const int*)&hS[c][0])[d];
    }
}

// ---------------------------------------------------------------------------
// Kernel 2: MFMA flash attention with ZERO in-loop LDS (R8 loop) on the
// tile-blocked hTi layout: every B-frag load (fx and hTi) is a contiguous
// 1-2 KB wave read — no strided gather.
// QK computed transposed (A=f-ext, B=g-ext): lane holds S[q=col][k=quad*4+r].
// After exp2, each lane's 8 P values are EXACTLY the PV A-frag under the k'
// permutation. l per-lane, shfl-reduced.
// launch_bounds(128,4) ONLY (R9/R10: min-waves>=8 hints force spill).
// No fused epilogue (R11: agent-scope fences = L2 writeback storm).
// Grid: QT*KS = 4608 blocks x 2 waves.
// ---------------------------------------------------------------------------
__global__ __launch_bounds__(128, 4) void attn_kernel(
    const short* __restrict__ fx, const short* __restrict__ gx,
    const short* __restrict__ hTi,
    float* __restrict__ l_acc, float* __restrict__ o_acc)
{
    __shared__ float red[32 * 33];            // epilogue-only, 4224 B

    const int tid  = threadIdx.x;
    const int wave = tid >> 6;
    const int lane = tid & 63;
    const int col  = lane & 15;
    const int quad = lane >> 4;

    const int blk = blockIdx.x;
    const int qt  = blk % QT;                 // query tile 0..575
    const int ks  = blk / QT;                 // key split 0..7
    const int b   = qt / (QT / BATCH);        // batch
    const int qbase   = (qt % (QT / BATCH)) * 32;
    const int rowbase = b * NTOK + qbase;

    // persistent B-operands for QK: g-ext for 2 query sub-tiles
    const bf16x8 agA = *(const bf16x8*)(gx + (size_t)(rowbase + col) * 32 + quad * 8);
    const bf16x8 agB = *(const bf16x8*)(gx + (size_t)(rowbase + 16 + col) * 32 + quad * 8);

    f32x4 oA0 = {0.f,0.f,0.f,0.f}, oA1 = {0.f,0.f,0.f,0.f};
    f32x4 oB0 = {0.f,0.f,0.f,0.f}, oB1 = {0.f,0.f,0.f,0.f};
    float lA = 0.f, lB = 0.f;
    const f32x4 zero4 = {0.f,0.f,0.f,0.f};

    const int kstart = ks * KEYS_PER_BLOCK + wave * KEYS_PER_WAVE;
    const short* fbase = fx + ((size_t)b * NTOK + kstart) * 32;
    // hTi base for this wave's first key tile; per-lane v offset folded in.
    // hb0: v=col -> col*32 ; hb1: v=16+col -> +512 shorts. Tile t -> +t*1024.
    const short* hbase = hTi + ((size_t)(b * NKTILE) + (kstart >> 5)) * 1024
                             + col * 32 + quad * 8;

    // preload tile 0
    bf16x8 fa0 = *(const bf16x8*)(fbase + (size_t)col * 32 + quad * 8);        // keys 0-15
    bf16x8 fa1 = *(const bf16x8*)(fbase + (size_t)(16 + col) * 32 + quad * 8); // keys 16-31
    bf16x8 hb0 = *(const bf16x8*)(hbase);
    bf16x8 hb1 = *(const bf16x8*)(hbase + 512);

    union PU { int i[4]; bf16x8 v; };

    for (int t = 0; t < NKT; ++t) {
        // QK transposed: lane holds S[q=col][k=quad*4+r]
        f32x4 t00 = __builtin_amdgcn_mfma_f32_16x16x32_bf16(fa0, agA, zero4, 0, 0, 0);
        f32x4 t01 = __builtin_amdgcn_mfma_f32_16x16x32_bf16(fa1, agA, zero4, 0, 0, 0);
        f32x4 t10 = __builtin_amdgcn_mfma_f32_16x16x32_bf16(fa0, agB, zero4, 0, 0, 0);
        f32x4 t11 = __builtin_amdgcn_mfma_f32_16x16x32_bf16(fa1, agB, zero4, 0, 0, 0);

        // prefetch tile t+1 (clamped; discarded on last iter)
        const int kn = (t + 1 < NKT) ? (t + 1) : 0;
        bf16x8 nf0 = *(const bf16x8*)(fbase + (size_t)(kn * KT + col) * 32 + quad * 8);
        bf16x8 nf1 = *(const bf16x8*)(fbase + (size_t)(kn * KT + 16 + col) * 32 + quad * 8);
        bf16x8 nh0 = *(const bf16x8*)(hbase + kn * 1024);
        bf16x8 nh1 = *(const bf16x8*)(hbase + kn * 1024 + 512);

        // exp2 + round-to-bf16 + pack: P registers ARE the PV A-frag
        PU pA, pB;
        {
            float e0 = __builtin_amdgcn_exp2f(t00[0]), e1 = __builtin_amdgcn_exp2f(t00[1]);
            float e2 = __builtin_amdgcn_exp2f(t00[2]), e3 = __builtin_amdgcn_exp2f(t00[3]);
            float e4 = __builtin_amdgcn_exp2f(t01[0]), e5 = __builtin_amdgcn_exp2f(t01[1]);
            float e6 = __builtin_amdgcn_exp2f(t01[2]), e7 = __builtin_amdgcn_exp2f(t01[3]);
            lA += (e0 + e1) + (e2 + e3) + (e4 + e5) + (e6 + e7);
            pA.i[0] = (int)__builtin_amdgcn_perm((unsigned)__float_as_int(e1) + 0x8000u,
                                                 (unsigned)__float_as_int(e0) + 0x8000u, 0x07060302u);
            pA.i[1] = (int)__builtin_amdgcn_perm((unsigned)__float_as_int(e3) + 0x8000u,
                                                 (unsigned)__float_as_int(e2) + 0x8000u, 0x07060302u);
            pA.i[2] = (int)__builtin_amdgcn_perm((unsigned)__float_as_int(e5) + 0x8000u,
                                                 (unsigned)__float_as_int(e4) + 0x8000u, 0x07060302u);
            pA.i[3] = (int)__builtin_amdgcn_perm((unsigned)__float_as_int(e7) + 0x8000u,
                                                 (unsigned)__float_as_int(e6) + 0x8000u, 0x07060302u);
        }
        {
            float e0 = __builtin_amdgcn_exp2f(t10[0]), e1 = __builtin_amdgcn_exp2f(t10[1]);
            float e2 = __builtin_amdgcn_exp2f(t10[2]), e3 = __builtin_amdgcn_exp2f(t10[3]);
            float e4 = __builtin_amdgcn_exp2f(t11[0]), e5 = __builtin_amdgcn_exp2f(t11[1]);
            float e6 = __builtin_amdgcn_exp2f(t11[2]), e7 = __builtin_amdgcn_exp2f(t11[3]);
            lB += (e0 + e1) + (e2 + e3) + (e4 + e5) + (e6 + e7);
            pB.i[0] = (int)__builtin_amdgcn_perm((unsigned)__float_as_int(e1) + 0x8000u,
                                                 (unsigned)__float_as_int(e0) + 0x8000u, 0x07060302u);
            pB.i[1] = (int)__builtin_amdgcn_perm((unsigned)__float_as_int(e3) + 0x8000u,
                                                 (unsigned)__float_as_int(e2) + 0x8000u, 0x07060302u);
            pB.i[2] = (int)__builtin_amdgcn_perm((unsigned)__float_as_int(e5) + 0x8000u,
                                                 (unsigned)__float_as_int(e4) + 0x8000u, 0x07060302u);
            pB.i[3] = (int)__builtin_amdgcn_perm((unsigned)__float_as_int(e7) + 0x8000u,
                                                 (unsigned)__float_as_int(e6) + 0x8000u, 0x07060302u);
        }

        // PV: A = packed P (direct), B = tile-blocked hTi frags
        oA0 = __builtin_amdgcn_mfma_f32_16x16x32_bf16(pA.v, hb0, oA0, 0, 0, 0);
        oA1 = __builtin_amdgcn_mfma_f32_16x16x32_bf16(pA.v, hb1, oA1, 0, 0, 0);
        oB0 = __builtin_amdgcn_mfma_f32_16x16x32_bf16(pB.v, hb0, oB0, 0, 0, 0);
        oB1 = __builtin_amdgcn_mfma_f32_16x16x32_bf16(pB.v, hb1, oB1, 0, 0, 0);

        fa0 = nf0; fa1 = nf1; hb0 = nh0; hb1 = nh1;
    }

    // l: reduce across quads (lanes col, col+16, col+32, col+48 share q=col)
    lA += __shfl_xor(lA, 16); lA += __shfl_xor(lA, 32);
    lB += __shfl_xor(lB, 16); lB += __shfl_xor(lB, 32);

    // cross-wave merge: wave1 stores to red, wave0 combines + global atomics.
    // O layout: lane holds O[q=quad*4+r][v=col] (oX0) / [v=16+col] (oX1).
    if (wave == 1) {
        #pragma unroll
        for (int r = 0; r < 4; ++r) {
            red[(quad * 4 + r) * 33 + col]           = oA0[r];
            red[(quad * 4 + r) * 33 + 16 + col]      = oA1[r];
            red[(16 + quad * 4 + r) * 33 + col]      = oB0[r];
            red[(16 + quad * 4 + r) * 33 + 16 + col] = oB1[r];
        }
        if (quad == 0) {
            red[col * 33 + 32]        = lA;
            red[(16 + col) * 33 + 32] = lB;
        }
    }
    __syncthreads();
    if (wave == 0) {
        #pragma unroll
        for (int r = 0; r < 4; ++r) {
            int qA = quad * 4 + r, qB = 16 + quad * 4 + r;
            atomicAdd(&o_acc[(size_t)(rowbase + qA) * 32 + col],      oA0[r] + red[qA * 33 + col]);
            atomicAdd(&o_acc[(size_t)(rowbase + qA) * 32 + 16 + col], oA1[r] + red[qA * 33 + 16 + col]);
            atomicAdd(&o_acc[(size_t)(rowbase + qB) * 32 + col],      oB0[r] + red[qB * 33 + col]);
            atomicAdd(&o_acc[(size_t)(rowbase + qB) * 32 + 16 + col], oB1[r] + red[qB * 33 + 16 + col]);
        }
        if (quad == 0) {
            atomicAdd(&l_acc[rowbase + col],      lA + red[col * 33 + 32]);
            atomicAdd(&l_acc[rowbase + 16 + col], lB + red[(16 + col) * 33 + 32]);
        }
    }
}

// ---------------------------------------------------------------------------
// Kernel 3: normalize + output projection + residual (fp32 weights).
// One wave per query: o[k] = o_acc/l ; out = gamma*(o@W4 + b4) + x
// ---------------------------------------------------------------------------
__global__ __launch_bounds__(256) void merge_kernel(
    const float* __restrict__ l_acc, const float* __restrict__ o_acc,
    const float* __restrict__ x,
    const float* __restrict__ W4, const float* __restrict__ b4,
    const float* __restrict__ gamma, float* __restrict__ out)
{
    __shared__ float oS[4][DV];
    int wave = threadIdx.x >> 6;
    int lane = threadIdx.x & 63;
    int row  = blockIdx.x * 4 + wave;     // < 18432 exactly

    float invL = 1.f / l_acc[row];
    if (lane < DV) {
        oS[wave][lane] = o_acc[(size_t)row * DV + lane] * invL;
    }
    __syncthreads();

    float dot = b4[lane];
    #pragma unroll
    for (int k = 0; k < DV; ++k) dot += oS[wave][k] * W4[k * 64 + lane];
    float gm  = gamma[0];
    float res = x[(size_t)row * 64 + lane];
    out[(size_t)row * 64 + lane] = gm * dot + res;
}

// ---------------------------------------------------------------------------
extern "C" void kernel_launch(void* const* d_in, const int* in_sizes, int n_in,
                              void* d_out, int out_size, void* d_ws, size_t ws_size,
                              hipStream_t stream) {
    const float* x     = (const float*)d_in[0];
    const float* W1    = (const float*)d_in[1];
    const float* b1    = (const float*)d_in[2];
    const float* W2    = (const float*)d_in[3];
    const float* b2    = (const float*)d_in[4];
    const float* W3    = (const float*)d_in[5];
    const float* b3    = (const float*)d_in[6];
    const float* W4    = (const float*)d_in[7];
    const float* b4    = (const float*)d_in[8];
    const float* gamma = (const float*)d_in[9];
    float* out = (float*)d_out;

    // Workspace: fx/gx/hTi bf16 (1.18 MB each) + l_acc + o_acc = 5.97 MB total
    short* fx    = (short*)d_ws;                       // 589824 shorts
    short* gx    = fx + (size_t)ROWS * 32;             // 589824 shorts
    short* hTi   = gx + (size_t)ROWS * 32;             // 589824 shorts
    float* l_acc = (float*)(hTi + (size_t)ROWS * 32);  // 18432 floats
    float* o_acc = l_acc + ROWS;                       // 589824 floats

    // proj (+ zeroing of l_acc/o_acc): 576 blocks x 512 threads
    proj_kernel<<<ROWS / PB, 512, 0, stream>>>(
        x, W1, b1, W2, b2, W3, b3, fx, gx, hTi, (float4*)l_acc);

    // attention: 576 query-tiles x 8 key-splits = 4608 blocks x 2 waves
    attn_kernel<<<QT * KS, 128, 0, stream>>>(fx, gx, hTi, l_acc, o_acc);

    // merge: 18432 queries / 4 waves per block
    merge_kernel<<<ROWS / 4, 256, 0, stream>>>(l_acc, o_acc, x, W4, b4, gamma, out);
}

// Round 14
// 139.186 us; speedup vs baseline: 2.4408x; 1.0077x over previous
//
#include <hip/hip_runtime.h>
#include <hip/hip_bf16.h>

// All reference dtypes are float32 (verified R3): inputs const float*, output float*.

#define BATCH 2
#define NTOK 9216        // 96*96
#define CCH 64
#define DV 32
#define KS 8                          // key splits (per block; x2 waves -> eff 16)
#define KEYS_PER_BLOCK (NTOK / KS)    // 1152
#define KEYS_PER_WAVE (KEYS_PER_BLOCK / 2)  // 576 (per wave)
#define KT 32                         // keys per MFMA tile
#define NKT (KEYS_PER_WAVE / KT)      // 18 tiles per wave
#define ROWS (BATCH * NTOK)           // 18432
#define QTB (ROWS / 64)               // 288 query tiles (64 q per block)
#define NKTILE (NTOK / 32)            // 288 key tiles per batch
#define LOG2E 1.44269504088896340736f
#define PB 32                         // proj rows per block
#define ZTOT 152064                   // float4s to zero: l_acc+o_acc

typedef __attribute__((ext_vector_type(8))) short bf16x8;   // 8 bf16 (4 VGPRs)
typedef __attribute__((ext_vector_type(4))) float f32x4;    // MFMA C/D

__device__ __forceinline__ short f2bf(float x) {
    __hip_bfloat16 h = __float2bfloat16(x);   // RNE
    return *(short*)&h;
}
__device__ __forceinline__ float bf2f(short s) {
    unsigned u = ((unsigned)(unsigned short)s) << 16;
    return *(float*)&u;
}

// ---------------------------------------------------------------------------
// Kernel 1: projections -> MFMA-ready bf16 operands + zeroing of l/o_acc.
//  gx[row][32]: [g_hi(8) | g_lo(8) | g_hi(8) | 0]   (g pre-scaled by log2e)
//  fx[key][32]: [f_hi(8) | f_hi(8) | f_lo(8) | 0]
//  hTi[b][key_tile][v][k']: TILE-BLOCKED transposed H (R13-verified: kills
//   the 18 KB row-stride gather). k' permutation
//   np(ni) = ((ni&15)>>2)*8 + (ni&3) + ((ni>>4)&1)*4 makes post-exp2 P
//   registers directly usable as the PV A-frag (R8-verified).
// ---------------------------------------------------------------------------
__global__ __launch_bounds__(512) void proj_kernel(
    const float* __restrict__ x,
    const float* __restrict__ W1, const float* __restrict__ b1,
    const float* __restrict__ W2, const float* __restrict__ b2,
    const float* __restrict__ W3, const float* __restrict__ b3,
    short* __restrict__ fx, short* __restrict__ gx, short* __restrict__ hTi,
    float4* __restrict__ zbase)
{
    __shared__ float xS[PB][CCH];        // 8 KB
    __shared__ short fgS[2][PB][32];     // 4 KB staging for fx, gx
    __shared__ short hS[32][PB + 2];     // 2.1 KB staging for hTi

    const int tid = threadIdx.x;
    const int r0  = blockIdx.x * PB;     // 32-row tile == one key tile

    // zero l_acc + o_acc: one float4 per thread, grid covers ZTOT
    {
        int zi = blockIdx.x * 512 + tid;
        if (zi < ZTOT) zbase[zi] = make_float4(0.f, 0.f, 0.f, 0.f);
    }

    // cooperative x load: 512 threads x float4 = 32 rows x 64 floats
    ((float4*)xS)[tid] = ((const float4*)(x + (size_t)r0 * CCH))[tid];
    __syncthreads();

    // phase 1: f (tid<256) / g (tid>=256) — wave-uniform split
    {
        const int half = tid >> 8;            // 0: f, 1: g
        const int rr   = (tid & 255) >> 3;    // 0..31
        const int c    = tid & 7;             // 0..7
        const float* xr = xS[rr];
        if (half == 0) {
            float acc = b1[c];
            #pragma unroll
            for (int k = 0; k < CCH; ++k) acc += xr[k] * W1[k * 8 + c];
            short hi = f2bf(acc);
            short lo = f2bf(acc - bf2f(hi));
            fgS[0][rr][c] = hi; fgS[0][rr][c + 8] = hi;
            fgS[0][rr][c + 16] = lo; fgS[0][rr][c + 24] = 0;
        } else {
            float acc = b2[c];
            #pragma unroll
            for (int k = 0; k < CCH; ++k) acc += xr[k] * W2[k * 8 + c];
            acc *= LOG2E;                 // fold log2(e) for exp2 inner loop
            short hi = f2bf(acc);
            short lo = f2bf(acc - bf2f(hi));
            fgS[1][rr][c] = hi; fgS[1][rr][c + 8] = lo;
            fgS[1][rr][c + 16] = hi; fgS[1][rr][c + 24] = 0;
        }
    }
    // phase 2: h — thread (c = tid&31, rbase = tid>>5) covers rows rbase, rbase+16
    {
        const int c = tid & 31;
        const int rbase = tid >> 5;
        #pragma unroll
        for (int s = 0; s < 2; ++s) {
            int rr = rbase + s * 16;
            float acc = b3[c];
            #pragma unroll
            for (int k = 0; k < CCH; ++k) acc += xS[rr][k] * W3[k * 32 + c];
            int np = ((rr & 15) >> 2) * 8 + (rr & 3) + ((rr >> 4) & 1) * 4;
            hS[c][np] = f2bf(acc);
        }
    }
    __syncthreads();

    // coalesced write-out (dwords)
    ((int*)(fx + (size_t)r0 * 32))[tid] = ((const int*)fgS[0])[tid];
    ((int*)(gx + (size_t)r0 * 32))[tid] = ((const int*)fgS[1])[tid];
    {
        const int b  = r0 / NTOK;
        const int n0 = r0 - b * NTOK;
        const int kt = n0 >> 5;               // key tile within batch
        const int c  = tid >> 4;              // v = 0..31
        const int d  = tid & 15;              // dword within 64B v-row
        ((int*)(hTi + ((size_t)(b * NKTILE + kt)) * 1024))[c * 16 + d] =
            ((const int*)&hS[c][0])[d];
    }
}

// ---------------------------------------------------------------------------
// Kernel 2: MFMA flash attention, Q=64/wave (4 query sub-tiles A-D).
// R14: per-tile f/h loads are query-count-independent -> 64 q/wave halves
// the L2 read stream (663->331 MB) and gives 8 independent QK chains of ILP.
// QK transposed (A=f-ext, B=g-ext): lane holds S[q=col][k=quad*4+r]; after
// exp2, P registers ARE the PV A-frag under the k' permutation (R8).
// Zero in-loop LDS; l per-lane, shfl-reduced.
// launch_bounds(128,4) ONLY (R9/R10: min-waves>=8 forces spill).
// Grid: QTB*KS = 288*8 = 2304 blocks x 2 waves.
// ---------------------------------------------------------------------------
__global__ __launch_bounds__(128, 4) void attn_kernel(
    const short* __restrict__ fx, const short* __restrict__ gx,
    const short* __restrict__ hTi,
    float* __restrict__ l_acc, float* __restrict__ o_acc)
{
    __shared__ float red[64 * 33];            // epilogue-only, 8448 B

    const int tid  = threadIdx.x;
    const int wave = tid >> 6;
    const int lane = tid & 63;
    const int col  = lane & 15;
    const int quad = lane >> 4;

    const int blk = blockIdx.x;
    const int qt  = blk % QTB;                // query tile 0..287
    const int ks  = blk / QTB;                // key split 0..7
    const int b   = qt / (QTB / BATCH);       // batch
    const int qbase   = (qt % (QTB / BATCH)) * 64;
    const int rowbase = b * NTOK + qbase;

    // persistent B-operands for QK: g-ext for 4 query sub-tiles
    const bf16x8 agA = *(const bf16x8*)(gx + (size_t)(rowbase + col) * 32 + quad * 8);
    const bf16x8 agB = *(const bf16x8*)(gx + (size_t)(rowbase + 16 + col) * 32 + quad * 8);
    const bf16x8 agC = *(const bf16x8*)(gx + (size_t)(rowbase + 32 + col) * 32 + quad * 8);
    const bf16x8 agD = *(const bf16x8*)(gx + (size_t)(rowbase + 48 + col) * 32 + quad * 8);

    f32x4 oA0 = {0,0,0,0}, oA1 = {0,0,0,0};
    f32x4 oB0 = {0,0,0,0}, oB1 = {0,0,0,0};
    f32x4 oC0 = {0,0,0,0}, oC1 = {0,0,0,0};
    f32x4 oD0 = {0,0,0,0}, oD1 = {0,0,0,0};
    float lA = 0.f, lB = 0.f, lC = 0.f, lD = 0.f;
    const f32x4 zero4 = {0,0,0,0};

    const int kstart = ks * KEYS_PER_BLOCK + wave * KEYS_PER_WAVE;
    const short* fbase = fx + ((size_t)b * NTOK + kstart) * 32;
    const short* hbase = hTi + ((size_t)(b * NKTILE) + (kstart >> 5)) * 1024
                             + col * 32 + quad * 8;

    // preload tile 0
    bf16x8 fa0 = *(const bf16x8*)(fbase + (size_t)col * 32 + quad * 8);
    bf16x8 fa1 = *(const bf16x8*)(fbase + (size_t)(16 + col) * 32 + quad * 8);
    bf16x8 hb0 = *(const bf16x8*)(hbase);
    bf16x8 hb1 = *(const bf16x8*)(hbase + 512);

    union PU { int i[4]; bf16x8 v; };

    #define EXPPACK(T0, T1, LSUM, P)                                            \
    {                                                                           \
        float e0 = __builtin_amdgcn_exp2f(T0[0]), e1 = __builtin_amdgcn_exp2f(T0[1]); \
        float e2 = __builtin_amdgcn_exp2f(T0[2]), e3 = __builtin_amdgcn_exp2f(T0[3]); \
        float e4 = __builtin_amdgcn_exp2f(T1[0]), e5 = __builtin_amdgcn_exp2f(T1[1]); \
        float e6 = __builtin_amdgcn_exp2f(T1[2]), e7 = __builtin_amdgcn_exp2f(T1[3]); \
        LSUM += (e0 + e1) + (e2 + e3) + (e4 + e5) + (e6 + e7);                  \
        P.i[0] = (int)__builtin_amdgcn_perm((unsigned)__float_as_int(e1) + 0x8000u, \
                                            (unsigned)__float_as_int(e0) + 0x8000u, 0x07060302u); \
        P.i[1] = (int)__builtin_amdgcn_perm((unsigned)__float_as_int(e3) + 0x8000u, \
                                            (unsigned)__float_as_int(e2) + 0x8000u, 0x07060302u); \
        P.i[2] = (int)__builtin_amdgcn_perm((unsigned)__float_as_int(e5) + 0x8000u, \
                                            (unsigned)__float_as_int(e4) + 0x8000u, 0x07060302u); \
        P.i[3] = (int)__builtin_amdgcn_perm((unsigned)__float_as_int(e7) + 0x8000u, \
                                            (unsigned)__float_as_int(e6) + 0x8000u, 0x07060302u); \
    }

    for (int t = 0; t < NKT; ++t) {
        // QK transposed for all 4 sub-tiles: lane holds S[q=col][k=quad*4+r]
        f32x4 tA0 = __builtin_amdgcn_mfma_f32_16x16x32_bf16(fa0, agA, zero4, 0, 0, 0);
        f32x4 tA1 = __builtin_amdgcn_mfma_f32_16x16x32_bf16(fa1, agA, zero4, 0, 0, 0);
        f32x4 tB0 = __builtin_amdgcn_mfma_f32_16x16x32_bf16(fa0, agB, zero4, 0, 0, 0);
        f32x4 tB1 = __builtin_amdgcn_mfma_f32_16x16x32_bf16(fa1, agB, zero4, 0, 0, 0);
        f32x4 tC0 = __builtin_amdgcn_mfma_f32_16x16x32_bf16(fa0, agC, zero4, 0, 0, 0);
        f32x4 tC1 = __builtin_amdgcn_mfma_f32_16x16x32_bf16(fa1, agC, zero4, 0, 0, 0);
        f32x4 tD0 = __builtin_amdgcn_mfma_f32_16x16x32_bf16(fa0, agD, zero4, 0, 0, 0);
        f32x4 tD1 = __builtin_amdgcn_mfma_f32_16x16x32_bf16(fa1, agD, zero4, 0, 0, 0);

        // prefetch tile t+1 (clamped; discarded on last iter)
        const int kn = (t + 1 < NKT) ? (t + 1) : 0;
        bf16x8 nf0 = *(const bf16x8*)(fbase + (size_t)(kn * KT + col) * 32 + quad * 8);
        bf16x8 nf1 = *(const bf16x8*)(fbase + (size_t)(kn * KT + 16 + col) * 32 + quad * 8);
        bf16x8 nh0 = *(const bf16x8*)(hbase + kn * 1024);
        bf16x8 nh1 = *(const bf16x8*)(hbase + kn * 1024 + 512);

        // exp2 + pack (P registers ARE the PV A-frag), then PV
        PU pA, pB, pC, pD;
        EXPPACK(tA0, tA1, lA, pA)
        EXPPACK(tB0, tB1, lB, pB)
        oA0 = __builtin_amdgcn_mfma_f32_16x16x32_bf16(pA.v, hb0, oA0, 0, 0, 0);
        oA1 = __builtin_amdgcn_mfma_f32_16x16x32_bf16(pA.v, hb1, oA1, 0, 0, 0);
        oB0 = __builtin_amdgcn_mfma_f32_16x16x32_bf16(pB.v, hb0, oB0, 0, 0, 0);
        oB1 = __builtin_amdgcn_mfma_f32_16x16x32_bf16(pB.v, hb1, oB1, 0, 0, 0);
        EXPPACK(tC0, tC1, lC, pC)
        EXPPACK(tD0, tD1, lD, pD)
        oC0 = __builtin_amdgcn_mfma_f32_16x16x32_bf16(pC.v, hb0, oC0, 0, 0, 0);
        oC1 = __builtin_amdgcn_mfma_f32_16x16x32_bf16(pC.v, hb1, oC1, 0, 0, 0);
        oD0 = __builtin_amdgcn_mfma_f32_16x16x32_bf16(pD.v, hb0, oD0, 0, 0, 0);
        oD1 = __builtin_amdgcn_mfma_f32_16x16x32_bf16(pD.v, hb1, oD1, 0, 0, 0);

        fa0 = nf0; fa1 = nf1; hb0 = nh0; hb1 = nh1;
    }
    #undef EXPPACK

    // l: reduce across quads (lanes col, col+16, col+32, col+48 share q=col)
    lA += __shfl_xor(lA, 16); lA += __shfl_xor(lA, 32);
    lB += __shfl_xor(lB, 16); lB += __shfl_xor(lB, 32);
    lC += __shfl_xor(lC, 16); lC += __shfl_xor(lC, 32);
    lD += __shfl_xor(lD, 16); lD += __shfl_xor(lD, 32);

    // cross-wave merge: wave1 stores to red, wave0 combines + global atomics.
    // Lane holds O[q = qoff + quad*4+r][v=col] (oX0) / [v=16+col] (oX1).
    if (wave == 1) {
        #pragma unroll
        for (int r = 0; r < 4; ++r) {
            int q = quad * 4 + r;
            red[(q)      * 33 + col]      = oA0[r];
            red[(q)      * 33 + 16 + col] = oA1[r];
            red[(q + 16) * 33 + col]      = oB0[r];
            red[(q + 16) * 33 + 16 + col] = oB1[r];
            red[(q + 32) * 33 + col]      = oC0[r];
            red[(q + 32) * 33 + 16 + col] = oC1[r];
            red[(q + 48) * 33 + col]      = oD0[r];
            red[(q + 48) * 33 + 16 + col] = oD1[r];
        }
        if (quad == 0) {
            red[(col)      * 33 + 32] = lA;
            red[(col + 16) * 33 + 32] = lB;
            red[(col + 32) * 33 + 32] = lC;
            red[(col + 48) * 33 + 32] = lD;
        }
    }
    __syncthreads();
    if (wave == 0) {
        #pragma unroll
        for (int r = 0; r < 4; ++r) {
            int q = quad * 4 + r;
            atomicAdd(&o_acc[(size_t)(rowbase + q)      * 32 + col],      oA0[r] + red[(q)      * 33 + col]);
            atomicAdd(&o_acc[(size_t)(rowbase + q)      * 32 + 16 + col], oA1[r] + red[(q)      * 33 + 16 + col]);
            atomicAdd(&o_acc[(size_t)(rowbase + q + 16) * 32 + col],      oB0[r] + red[(q + 16) * 33 + col]);
            atomicAdd(&o_acc[(size_t)(rowbase + q + 16) * 32 + 16 + col], oB1[r] + red[(q + 16) * 33 + 16 + col]);
            atomicAdd(&o_acc[(size_t)(rowbase + q + 32) * 32 + col],      oC0[r] + red[(q + 32) * 33 + col]);
            atomicAdd(&o_acc[(size_t)(rowbase + q + 32) * 32 + 16 + col], oC1[r] + red[(q + 32) * 33 + 16 + col]);
            atomicAdd(&o_acc[(size_t)(rowbase + q + 48) * 32 + col],      oD0[r] + red[(q + 48) * 33 + col]);
            atomicAdd(&o_acc[(size_t)(rowbase + q + 48) * 32 + 16 + col], oD1[r] + red[(q + 48) * 33 + 16 + col]);
        }
        if (quad == 0) {
            atomicAdd(&l_acc[rowbase + col],      lA + red[(col)      * 33 + 32]);
            atomicAdd(&l_acc[rowbase + 16 + col], lB + red[(col + 16) * 33 + 32]);
            atomicAdd(&l_acc[rowbase + 32 + col], lC + red[(col + 32) * 33 + 32]);
            atomicAdd(&l_acc[rowbase + 48 + col], lD + red[(col + 48) * 33 + 32]);
        }
    }
}

// ---------------------------------------------------------------------------
// Kernel 3: normalize + output projection + residual (fp32 weights).
// One wave per query: o[k] = o_acc/l ; out = gamma*(o@W4 + b4) + x
// ---------------------------------------------------------------------------
__global__ __launch_bounds__(256) void merge_kernel(
    const float* __restrict__ l_acc, const float* __restrict__ o_acc,
    const float* __restrict__ x,
    const float* __restrict__ W4, const float* __restrict__ b4,
    const float* __restrict__ gamma, float* __restrict__ out)
{
    __shared__ float oS[4][DV];
    int wave = threadIdx.x >> 6;
    int lane = threadIdx.x & 63;
    int row  = blockIdx.x * 4 + wave;     // < 18432 exactly

    float invL = 1.f / l_acc[row];
    if (lane < DV) {
        oS[wave][lane] = o_acc[(size_t)row * DV + lane] * invL;
    }
    __syncthreads();

    float dot = b4[lane];
    #pragma unroll
    for (int k = 0; k < DV; ++k) dot += oS[wave][k] * W4[k * 64 + lane];
    float gm  = gamma[0];
    float res = x[(size_t)row * 64 + lane];
    out[(size_t)row * 64 + lane] = gm * dot + res;
}

// ---------------------------------------------------------------------------
extern "C" void kernel_launch(void* const* d_in, const int* in_sizes, int n_in,
                              void* d_out, int out_size, void* d_ws, size_t ws_size,
                              hipStream_t stream) {
    const float* x     = (const float*)d_in[0];
    const float* W1    = (const float*)d_in[1];
    const float* b1    = (const float*)d_in[2];
    const float* W2    = (const float*)d_in[3];
    const float* b2    = (const float*)d_in[4];
    const float* W3    = (const float*)d_in[5];
    const float* b3    = (const float*)d_in[6];
    const float* W4    = (const float*)d_in[7];
    const float* b4    = (const float*)d_in[8];
    const float* gamma = (const float*)d_in[9];
    float* out = (float*)d_out;

    // Workspace: fx/gx/hTi bf16 (1.18 MB each) + l_acc + o_acc = 5.97 MB total
    short* fx    = (short*)d_ws;                       // 589824 shorts
    short* gx    = fx + (size_t)ROWS * 32;             // 589824 shorts
    short* hTi   = gx + (size_t)ROWS * 32;             // 589824 shorts
    float* l_acc = (float*)(hTi + (size_t)ROWS * 32);  // 18432 floats
    float* o_acc = l_acc + ROWS;                       // 589824 floats

    // proj (+ zeroing of l_acc/o_acc): 576 blocks x 512 threads
    proj_kernel<<<ROWS / PB, 512, 0, stream>>>(
        x, W1, b1, W2, b2, W3, b3, fx, gx, hTi, (float4*)l_acc);

    // attention: 288 query-tiles (64 q) x 8 key-splits = 2304 blocks x 2 waves
    attn_kernel<<<QTB * KS, 128, 0, stream>>>(fx, gx, hTi, l_acc, o_acc);

    // merge: 18432 queries / 4 waves per block
    merge_kernel<<<ROWS / 4, 256, 0, stream>>>(l_acc, o_acc, x, W4, b4, gamma, out);
}

// Round 15
// 127.818 us; speedup vs baseline: 2.6578x; 1.0889x over previous
//
#include <hip/hip_runtime.h>
#include <hip/hip_bf16.h>

// All reference dtypes are float32 (verified R3): inputs const float*, output float*.

#define BATCH 2
#define NTOK 9216        // 96*96
#define CCH 64
#define DV 32
#define KS 8                          // key splits (per block; x4 waves -> eff 32)
#define KEYS_PER_BLOCK (NTOK / KS)    // 1152
#define KEYS_PER_WAVE (KEYS_PER_BLOCK / 4)  // 288 (per wave)
#define KT 32                         // keys per MFMA tile
#define NKT (KEYS_PER_WAVE / KT)      // 9 tiles per wave
#define ROWS (BATCH * NTOK)           // 18432
#define QTB (ROWS / 64)               // 288 query tiles (64 q per block)
#define NKTILE (NTOK / 32)            // 288 key tiles per batch
#define LOG2E 1.44269504088896340736f
#define PB 32                         // proj rows per block
#define XPAD 68                       // xS row stride (floats): kills 8-way conflicts
#define ZTOT 152064                   // float4s to zero: l_acc+o_acc

typedef __attribute__((ext_vector_type(8))) short bf16x8;   // 8 bf16 (4 VGPRs)
typedef __attribute__((ext_vector_type(4))) float f32x4;    // MFMA C/D

__device__ __forceinline__ short f2bf(float x) {
    __hip_bfloat16 h = __float2bfloat16(x);   // RNE
    return *(short*)&h;
}
__device__ __forceinline__ float bf2f(short s) {
    unsigned u = ((unsigned)(unsigned short)s) << 16;
    return *(float*)&u;
}

// ---------------------------------------------------------------------------
// Kernel 1: projections -> MFMA-ready bf16 operands + zeroing of l/o_acc.
//  gx[row][32]: [g_hi(8) | g_lo(8) | g_hi(8) | 0]   (g pre-scaled by log2e)
//  fx[key][32]: [f_hi(8) | f_hi(8) | f_lo(8) | 0]
//  hTi[b][key_tile][v][k']: TILE-BLOCKED transposed H (R13-verified).
//   k' perm np(ni) = ((ni&15)>>2)*8 + (ni&3) + ((ni>>4)&1)*4 makes post-exp2
//   P registers directly usable as the PV A-frag (R8-verified).
//  xS stride 68 (R15): phase-1 reads were 8-way bank-conflicted at stride 64.
// ---------------------------------------------------------------------------
__global__ __launch_bounds__(512) void proj_kernel(
    const float* __restrict__ x,
    const float* __restrict__ W1, const float* __restrict__ b1,
    const float* __restrict__ W2, const float* __restrict__ b2,
    const float* __restrict__ W3, const float* __restrict__ b3,
    short* __restrict__ fx, short* __restrict__ gx, short* __restrict__ hTi,
    float4* __restrict__ zbase)
{
    __shared__ float xS[PB * XPAD];      // 8.5 KB (padded rows)
    __shared__ short fgS[2][PB][32];     // 4 KB staging for fx, gx
    __shared__ short hS[32][PB + 2];     // 2.1 KB staging for hTi

    const int tid = threadIdx.x;
    const int r0  = blockIdx.x * PB;     // 32-row tile == one key tile

    // zero l_acc + o_acc: one float4 per thread, grid covers ZTOT
    {
        int zi = blockIdx.x * 512 + tid;
        if (zi < ZTOT) zbase[zi] = make_float4(0.f, 0.f, 0.f, 0.f);
    }

    // cooperative x load: 512 threads x float4 = 32 rows x 64 floats
    {
        const int row = tid >> 4, c4 = tid & 15;
        ((float4*)(xS + row * XPAD))[c4] =
            ((const float4*)(x + (size_t)(r0 + row) * CCH))[c4];
    }
    __syncthreads();

    // phase 1: f (tid<256) / g (tid>=256) — wave-uniform split
    {
        const int half = tid >> 8;            // 0: f, 1: g
        const int rr   = (tid & 255) >> 3;    // 0..31
        const int c    = tid & 7;             // 0..7
        const float* xr = xS + rr * XPAD;
        if (half == 0) {
            float acc = b1[c];
            #pragma unroll
            for (int k = 0; k < CCH; ++k) acc += xr[k] * W1[k * 8 + c];
            short hi = f2bf(acc);
            short lo = f2bf(acc - bf2f(hi));
            fgS[0][rr][c] = hi; fgS[0][rr][c + 8] = hi;
            fgS[0][rr][c + 16] = lo; fgS[0][rr][c + 24] = 0;
        } else {
            float acc = b2[c];
            #pragma unroll
            for (int k = 0; k < CCH; ++k) acc += xr[k] * W2[k * 8 + c];
            acc *= LOG2E;                 // fold log2(e) for exp2 inner loop
            short hi = f2bf(acc);
            short lo = f2bf(acc - bf2f(hi));
            fgS[1][rr][c] = hi; fgS[1][rr][c + 8] = lo;
            fgS[1][rr][c + 16] = hi; fgS[1][rr][c + 24] = 0;
        }
    }
    // phase 2: h — thread (c = tid&31, rbase = tid>>5) covers rows rbase, rbase+16
    {
        const int c = tid & 31;
        const int rbase = tid >> 5;
        #pragma unroll
        for (int s = 0; s < 2; ++s) {
            int rr = rbase + s * 16;
            float acc = b3[c];
            #pragma unroll
            for (int k = 0; k < CCH; ++k) acc += xS[rr * XPAD + k] * W3[k * 32 + c];
            int np = ((rr & 15) >> 2) * 8 + (rr & 3) + ((rr >> 4) & 1) * 4;
            hS[c][np] = f2bf(acc);
        }
    }
    __syncthreads();

    // coalesced write-out (dwords)
    ((int*)(fx + (size_t)r0 * 32))[tid] = ((const int*)fgS[0])[tid];
    ((int*)(gx + (size_t)r0 * 32))[tid] = ((const int*)fgS[1])[tid];
    {
        const int b  = r0 / NTOK;
        const int n0 = r0 - b * NTOK;
        const int kt = n0 >> 5;               // key tile within batch
        const int c  = tid >> 4;              // v = 0..31
        const int d  = tid & 15;              // dword within 64B v-row
        ((int*)(hTi + ((size_t)(b * NKTILE + kt)) * 1024))[c * 16 + d] =
            ((const int*)&hS[c][0])[d];
    }
}

// ---------------------------------------------------------------------------
// Kernel 2: MFMA flash attention, Q=64/wave, 4 waves/block (R15).
// R14 halved L2 traffic but also halved TLP (occupancy 26%); R15 restores
// 9216 waves by splitting each block's keys across 4 waves (NKT=9/wave),
// atomics unchanged (one set per block via 3-round LDS merge).
// l computed via MFMA (B=ones) — off the 40%-busy VALU pipe, no end-shfl.
// QK transposed (A=f-ext, B=g-ext); post-exp2 P registers ARE the PV A-frag
// under the k' permutation (R8). Zero in-loop LDS.
// launch_bounds(256,4): VGPR cap 128 — same as R8-R14's (128,4); NOT the
// R9/R10 min-waves>=8 spill trap.
// Grid: QTB*KS = 288*8 = 2304 blocks x 256 threads.
// ---------------------------------------------------------------------------
__global__ __launch_bounds__(256, 4) void attn_kernel(
    const short* __restrict__ fx, const short* __restrict__ gx,
    const short* __restrict__ hTi,
    float* __restrict__ l_acc, float* __restrict__ o_acc)
{
    __shared__ float red[64 * 33];            // epilogue-only, 8448 B

    const int tid  = threadIdx.x;
    const int wave = tid >> 6;                // 0..3
    const int lane = tid & 63;
    const int col  = lane & 15;
    const int quad = lane >> 4;

    const int blk = blockIdx.x;
    const int qt  = blk % QTB;                // query tile 0..287
    const int ks  = blk / QTB;                // key split 0..7
    const int b   = qt / (QTB / BATCH);       // batch
    const int qbase   = (qt % (QTB / BATCH)) * 64;
    const int rowbase = b * NTOK + qbase;

    // persistent B-operands for QK: g-ext for 4 query sub-tiles
    const bf16x8 agA = *(const bf16x8*)(gx + (size_t)(rowbase + col) * 32 + quad * 8);
    const bf16x8 agB = *(const bf16x8*)(gx + (size_t)(rowbase + 16 + col) * 32 + quad * 8);
    const bf16x8 agC = *(const bf16x8*)(gx + (size_t)(rowbase + 32 + col) * 32 + quad * 8);
    const bf16x8 agD = *(const bf16x8*)(gx + (size_t)(rowbase + 48 + col) * 32 + quad * 8);

    bf16x8 ones;
    #pragma unroll
    for (int j = 0; j < 8; ++j) ones[j] = (short)0x3F80;   // bf16 1.0

    f32x4 oA0 = {0,0,0,0}, oA1 = {0,0,0,0};
    f32x4 oB0 = {0,0,0,0}, oB1 = {0,0,0,0};
    f32x4 oC0 = {0,0,0,0}, oC1 = {0,0,0,0};
    f32x4 oD0 = {0,0,0,0}, oD1 = {0,0,0,0};
    f32x4 lfA = {0,0,0,0}, lfB = {0,0,0,0};
    f32x4 lfC = {0,0,0,0}, lfD = {0,0,0,0};
    const f32x4 zero4 = {0,0,0,0};

    const int kstart = ks * KEYS_PER_BLOCK + wave * KEYS_PER_WAVE;
    const short* fbase = fx + ((size_t)b * NTOK + kstart) * 32;
    const short* hbase = hTi + ((size_t)(b * NKTILE) + (kstart >> 5)) * 1024
                             + col * 32 + quad * 8;

    // preload tile 0
    bf16x8 fa0 = *(const bf16x8*)(fbase + (size_t)col * 32 + quad * 8);
    bf16x8 fa1 = *(const bf16x8*)(fbase + (size_t)(16 + col) * 32 + quad * 8);
    bf16x8 hb0 = *(const bf16x8*)(hbase);
    bf16x8 hb1 = *(const bf16x8*)(hbase + 512);

    union PU { int i[4]; bf16x8 v; };

    #define EXPPACK(T0, T1, P)                                                  \
    {                                                                           \
        float e0 = __builtin_amdgcn_exp2f(T0[0]), e1 = __builtin_amdgcn_exp2f(T0[1]); \
        float e2 = __builtin_amdgcn_exp2f(T0[2]), e3 = __builtin_amdgcn_exp2f(T0[3]); \
        float e4 = __builtin_amdgcn_exp2f(T1[0]), e5 = __builtin_amdgcn_exp2f(T1[1]); \
        float e6 = __builtin_amdgcn_exp2f(T1[2]), e7 = __builtin_amdgcn_exp2f(T1[3]); \
        P.i[0] = (int)__builtin_amdgcn_perm((unsigned)__float_as_int(e1) + 0x8000u, \
                                            (unsigned)__float_as_int(e0) + 0x8000u, 0x07060302u); \
        P.i[1] = (int)__builtin_amdgcn_perm((unsigned)__float_as_int(e3) + 0x8000u, \
                                            (unsigned)__float_as_int(e2) + 0x8000u, 0x07060302u); \
        P.i[2] = (int)__builtin_amdgcn_perm((unsigned)__float_as_int(e5) + 0x8000u, \
                                            (unsigned)__float_as_int(e4) + 0x8000u, 0x07060302u); \
        P.i[3] = (int)__builtin_amdgcn_perm((unsigned)__float_as_int(e7) + 0x8000u, \
                                            (unsigned)__float_as_int(e6) + 0x8000u, 0x07060302u); \
    }

    for (int t = 0; t < NKT; ++t) {
        // QK transposed for all 4 sub-tiles: lane holds S[q=col][k=quad*4+r]
        f32x4 tA0 = __builtin_amdgcn_mfma_f32_16x16x32_bf16(fa0, agA, zero4, 0, 0, 0);
        f32x4 tA1 = __builtin_amdgcn_mfma_f32_16x16x32_bf16(fa1, agA, zero4, 0, 0, 0);
        f32x4 tB0 = __builtin_amdgcn_mfma_f32_16x16x32_bf16(fa0, agB, zero4, 0, 0, 0);
        f32x4 tB1 = __builtin_amdgcn_mfma_f32_16x16x32_bf16(fa1, agB, zero4, 0, 0, 0);
        f32x4 tC0 = __builtin_amdgcn_mfma_f32_16x16x32_bf16(fa0, agC, zero4, 0, 0, 0);
        f32x4 tC1 = __builtin_amdgcn_mfma_f32_16x16x32_bf16(fa1, agC, zero4, 0, 0, 0);
        f32x4 tD0 = __builtin_amdgcn_mfma_f32_16x16x32_bf16(fa0, agD, zero4, 0, 0, 0);
        f32x4 tD1 = __builtin_amdgcn_mfma_f32_16x16x32_bf16(fa1, agD, zero4, 0, 0, 0);

        // prefetch tile t+1 (clamped; discarded on last iter)
        const int kn = (t + 1 < NKT) ? (t + 1) : 0;
        bf16x8 nf0 = *(const bf16x8*)(fbase + (size_t)(kn * KT + col) * 32 + quad * 8);
        bf16x8 nf1 = *(const bf16x8*)(fbase + (size_t)(kn * KT + 16 + col) * 32 + quad * 8);
        bf16x8 nh0 = *(const bf16x8*)(hbase + kn * 1024);
        bf16x8 nh1 = *(const bf16x8*)(hbase + kn * 1024 + 512);

        // exp2 + pack (P registers ARE the PV A-frag), then PV + l-MFMA
        PU pA, pB, pC, pD;
        EXPPACK(tA0, tA1, pA)
        EXPPACK(tB0, tB1, pB)
        oA0 = __builtin_amdgcn_mfma_f32_16x16x32_bf16(pA.v, hb0, oA0, 0, 0, 0);
        oA1 = __builtin_amdgcn_mfma_f32_16x16x32_bf16(pA.v, hb1, oA1, 0, 0, 0);
        lfA = __builtin_amdgcn_mfma_f32_16x16x32_bf16(pA.v, ones, lfA, 0, 0, 0);
        oB0 = __builtin_amdgcn_mfma_f32_16x16x32_bf16(pB.v, hb0, oB0, 0, 0, 0);
        oB1 = __builtin_amdgcn_mfma_f32_16x16x32_bf16(pB.v, hb1, oB1, 0, 0, 0);
        lfB = __builtin_amdgcn_mfma_f32_16x16x32_bf16(pB.v, ones, lfB, 0, 0, 0);
        EXPPACK(tC0, tC1, pC)
        EXPPACK(tD0, tD1, pD)
        oC0 = __builtin_amdgcn_mfma_f32_16x16x32_bf16(pC.v, hb0, oC0, 0, 0, 0);
        oC1 = __builtin_amdgcn_mfma_f32_16x16x32_bf16(pC.v, hb1, oC1, 0, 0, 0);
        lfC = __builtin_amdgcn_mfma_f32_16x16x32_bf16(pC.v, ones, lfC, 0, 0, 0);
        oD0 = __builtin_amdgcn_mfma_f32_16x16x32_bf16(pD.v, hb0, oD0, 0, 0, 0);
        oD1 = __builtin_amdgcn_mfma_f32_16x16x32_bf16(pD.v, hb1, oD1, 0, 0, 0);
        lfD = __builtin_amdgcn_mfma_f32_16x16x32_bf16(pD.v, ones, lfD, 0, 0, 0);

        fa0 = nf0; fa1 = nf1; hb0 = nh0; hb1 = nh1;
    }
    #undef EXPPACK

    // 3-round cross-wave merge in one 8.4 KB buffer: wave w publishes,
    // wave 0 accumulates into registers; then wave 0 issues global atomics.
    // Lane holds O[q=qoff+quad*4+r][v=col] (oX0) / [v=16+col] (oX1);
    // lfX[r] = l[q=qoff+quad*4+r] (replicated across col lanes).
    for (int w = 1; w < 4; ++w) {
        if (wave == w) {
            #pragma unroll
            for (int r = 0; r < 4; ++r) {
                int q = quad * 4 + r;
                red[(q)      * 33 + col]      = oA0[r];
                red[(q)      * 33 + 16 + col] = oA1[r];
                red[(q + 16) * 33 + col]      = oB0[r];
                red[(q + 16) * 33 + 16 + col] = oB1[r];
                red[(q + 32) * 33 + col]      = oC0[r];
                red[(q + 32) * 33 + 16 + col] = oC1[r];
                red[(q + 48) * 33 + col]      = oD0[r];
                red[(q + 48) * 33 + 16 + col] = oD1[r];
            }
            if (col == 0) {
                #pragma unroll
                for (int r = 0; r < 4; ++r) {
                    int q = quad * 4 + r;
                    red[(q)      * 33 + 32] = lfA[r];
                    red[(q + 16) * 33 + 32] = lfB[r];
                    red[(q + 32) * 33 + 32] = lfC[r];
                    red[(q + 48) * 33 + 32] = lfD[r];
                }
            }
        }
        __syncthreads();
        if (wave == 0) {
            #pragma unroll
            for (int r = 0; r < 4; ++r) {
                int q = quad * 4 + r;
                oA0[r] += red[(q)      * 33 + col];
                oA1[r] += red[(q)      * 33 + 16 + col];
                oB0[r] += red[(q + 16) * 33 + col];
                oB1[r] += red[(q + 16) * 33 + 16 + col];
                oC0[r] += red[(q + 32) * 33 + col];
                oC1[r] += red[(q + 32) * 33 + 16 + col];
                oD0[r] += red[(q + 48) * 33 + col];
                oD1[r] += red[(q + 48) * 33 + 16 + col];
                lfA[r] += red[(q)      * 33 + 32];
                lfB[r] += red[(q + 16) * 33 + 32];
                lfC[r] += red[(q + 32) * 33 + 32];
                lfD[r] += red[(q + 48) * 33 + 32];
            }
        }
        __syncthreads();
    }
    if (wave == 0) {
        #pragma unroll
        for (int r = 0; r < 4; ++r) {
            int q = quad * 4 + r;
            atomicAdd(&o_acc[(size_t)(rowbase + q)      * 32 + col],      oA0[r]);
            atomicAdd(&o_acc[(size_t)(rowbase + q)      * 32 + 16 + col], oA1[r]);
            atomicAdd(&o_acc[(size_t)(rowbase + q + 16) * 32 + col],      oB0[r]);
            atomicAdd(&o_acc[(size_t)(rowbase + q + 16) * 32 + 16 + col], oB1[r]);
            atomicAdd(&o_acc[(size_t)(rowbase + q + 32) * 32 + col],      oC0[r]);
            atomicAdd(&o_acc[(size_t)(rowbase + q + 32) * 32 + 16 + col], oC1[r]);
            atomicAdd(&o_acc[(size_t)(rowbase + q + 48) * 32 + col],      oD0[r]);
            atomicAdd(&o_acc[(size_t)(rowbase + q + 48) * 32 + 16 + col], oD1[r]);
        }
        if (col == 0) {
            #pragma unroll
            for (int r = 0; r < 4; ++r) {
                int q = quad * 4 + r;
                atomicAdd(&l_acc[rowbase + q],      lfA[r]);
                atomicAdd(&l_acc[rowbase + q + 16], lfB[r]);
                atomicAdd(&l_acc[rowbase + q + 32], lfC[r]);
                atomicAdd(&l_acc[rowbase + q + 48], lfD[r]);
            }
        }
    }
}

// ---------------------------------------------------------------------------
// Kernel 3: normalize + output projection + residual (fp32 weights).
// One wave per query: o[k] = o_acc/l ; out = gamma*(o@W4 + b4) + x
// ---------------------------------------------------------------------------
__global__ __launch_bounds__(256) void merge_kernel(
    const float* __restrict__ l_acc, const float* __restrict__ o_acc,
    const float* __restrict__ x,
    const float* __restrict__ W4, const float* __restrict__ b4,
    const float* __restrict__ gamma, float* __restrict__ out)
{
    __shared__ float oS[4][DV];
    int wave = threadIdx.x >> 6;
    int lane = threadIdx.x & 63;
    int row  = blockIdx.x * 4 + wave;     // < 18432 exactly

    float invL = 1.f / l_acc[row];
    if (lane < DV) {
        oS[wave][lane] = o_acc[(size_t)row * DV + lane] * invL;
    }
    __syncthreads();

    float dot = b4[lane];
    #pragma unroll
    for (int k = 0; k < DV; ++k) dot += oS[wave][k] * W4[k * 64 + lane];
    float gm  = gamma[0];
    float res = x[(size_t)row * 64 + lane];
    out[(size_t)row * 64 + lane] = gm * dot + res;
}

// ---------------------------------------------------------------------------
extern "C" void kernel_launch(void* const* d_in, const int* in_sizes, int n_in,
                              void* d_out, int out_size, void* d_ws, size_t ws_size,
                              hipStream_t stream) {
    const float* x     = (const float*)d_in[0];
    const float* W1    = (const float*)d_in[1];
    const float* b1    = (const float*)d_in[2];
    const float* W2    = (const float*)d_in[3];
    const float* b2    = (const float*)d_in[4];
    const float* W3    = (const float*)d_in[5];
    const float* b3    = (const float*)d_in[6];
    const float* W4    = (const float*)d_in[7];
    const float* b4    = (const float*)d_in[8];
    const float* gamma = (const float*)d_in[9];
    float* out = (float*)d_out;

    // Workspace: fx/gx/hTi bf16 (1.18 MB each) + l_acc + o_acc = 5.97 MB total
    short* fx    = (short*)d_ws;                       // 589824 shorts
    short* gx    = fx + (size_t)ROWS * 32;             // 589824 shorts
    short* hTi   = gx + (size_t)ROWS * 32;             // 589824 shorts
    float* l_acc = (float*)(hTi + (size_t)ROWS * 32);  // 18432 floats
    float* o_acc = l_acc + ROWS;                       // 589824 floats

    // proj (+ zeroing of l_acc/o_acc): 576 blocks x 512 threads
    proj_kernel<<<ROWS / PB, 512, 0, stream>>>(
        x, W1, b1, W2, b2, W3, b3, fx, gx, hTi, (float4*)l_acc);

    // attention: 288 query-tiles (64 q) x 8 key-splits = 2304 blocks x 4 waves
    attn_kernel<<<QTB * KS, 256, 0, stream>>>(fx, gx, hTi, l_acc, o_acc);

    // merge: 18432 queries / 4 waves per block
    merge_kernel<<<ROWS / 4, 256, 0, stream>>>(l_acc, o_acc, x, W4, b4, gamma, out);
}

// Round 16
// 125.742 us; speedup vs baseline: 2.7017x; 1.0165x over previous
//
#include <hip/hip_runtime.h>
#include <hip/hip_bf16.h>

// All reference dtypes are float32 (verified R3): inputs const float*, output float*.

#define BATCH 2
#define NTOK 9216        // 96*96
#define CCH 64
#define DV 32
#define KS 4                          // key splits (per block; x4 waves -> eff 16)
#define KEYS_PER_BLOCK (NTOK / KS)    // 2304
#define KEYS_PER_WAVE (KEYS_PER_BLOCK / 4)  // 576 (per wave)
#define KT 32                         // keys per MFMA tile
#define NKT (KEYS_PER_WAVE / KT)      // 18 tiles per wave
#define ROWS (BATCH * NTOK)           // 18432
#define QTB (ROWS / 64)               // 288 query tiles (64 q per block)
#define NKTILE (NTOK / 32)            // 288 key tiles per batch
#define LOG2E 1.44269504088896340736f
#define PB 32                         // proj rows per block
#define XPAD 68                       // xS row stride (floats): conflict-free, 16B-aligned
#define ZTOT 152064                   // float4s to zero: l_acc+o_acc

typedef __attribute__((ext_vector_type(8))) short bf16x8;   // 8 bf16 (4 VGPRs)
typedef __attribute__((ext_vector_type(4))) float f32x4;    // MFMA C/D

__device__ __forceinline__ short f2bf(float x) {
    __hip_bfloat16 h = __float2bfloat16(x);   // RNE
    return *(short*)&h;
}
__device__ __forceinline__ float bf2f(short s) {
    unsigned u = ((unsigned)(unsigned short)s) << 16;
    return *(float*)&u;
}

// ---------------------------------------------------------------------------
// Kernel 1: projections -> MFMA-ready bf16 operands + zeroing of l/o_acc.
//  gx[row][32]: [g_hi(8) | g_lo(8) | g_hi(8) | 0]   (g pre-scaled by log2e)
//  fx[key][32]: [f_hi(8) | f_hi(8) | f_lo(8) | 0]
//  hTi[b][key_tile][v][k']: TILE-BLOCKED transposed H (R13-verified).
//   k' perm np(ni) = ((ni&15)>>2)*8 + (ni&3) + ((ni>>4)&1)*4 makes post-exp2
//   P registers directly usable as the PV A-frag (R8-verified).
//  R16: MAC loops read xS via float4 (48 LDS inst/thread vs 192).
// ---------------------------------------------------------------------------
__global__ __launch_bounds__(512) void proj_kernel(
    const float* __restrict__ x,
    const float* __restrict__ W1, const float* __restrict__ b1,
    const float* __restrict__ W2, const float* __restrict__ b2,
    const float* __restrict__ W3, const float* __restrict__ b3,
    short* __restrict__ fx, short* __restrict__ gx, short* __restrict__ hTi,
    float4* __restrict__ zbase)
{
    __shared__ float xS[PB * XPAD];      // 8.5 KB (padded rows, 272B stride)
    __shared__ short fgS[2][PB][32];     // 4 KB staging for fx, gx
    __shared__ short hS[32][PB + 2];     // 2.1 KB staging for hTi

    const int tid = threadIdx.x;
    const int r0  = blockIdx.x * PB;     // 32-row tile == one key tile

    // zero l_acc + o_acc: one float4 per thread, grid covers ZTOT
    {
        int zi = blockIdx.x * 512 + tid;
        if (zi < ZTOT) zbase[zi] = make_float4(0.f, 0.f, 0.f, 0.f);
    }

    // cooperative x load: 512 threads x float4 = 32 rows x 64 floats
    {
        const int row = tid >> 4, c4 = tid & 15;
        ((float4*)(xS + row * XPAD))[c4] =
            ((const float4*)(x + (size_t)(r0 + row) * CCH))[c4];
    }
    __syncthreads();

    // phase 1: f (tid<256) / g (tid>=256) — wave-uniform split
    {
        const int half = tid >> 8;            // 0: f, 1: g
        const int rr   = (tid & 255) >> 3;    // 0..31
        const int c    = tid & 7;             // 0..7
        const float4* xr4 = (const float4*)(xS + rr * XPAD);
        if (half == 0) {
            float acc = b1[c];
            #pragma unroll
            for (int k4 = 0; k4 < 16; ++k4) {
                float4 xv = xr4[k4];
                acc += xv.x * W1[(4*k4+0) * 8 + c] + xv.y * W1[(4*k4+1) * 8 + c]
                     + xv.z * W1[(4*k4+2) * 8 + c] + xv.w * W1[(4*k4+3) * 8 + c];
            }
            short hi = f2bf(acc);
            short lo = f2bf(acc - bf2f(hi));
            fgS[0][rr][c] = hi; fgS[0][rr][c + 8] = hi;
            fgS[0][rr][c + 16] = lo; fgS[0][rr][c + 24] = 0;
        } else {
            float acc = b2[c];
            #pragma unroll
            for (int k4 = 0; k4 < 16; ++k4) {
                float4 xv = xr4[k4];
                acc += xv.x * W2[(4*k4+0) * 8 + c] + xv.y * W2[(4*k4+1) * 8 + c]
                     + xv.z * W2[(4*k4+2) * 8 + c] + xv.w * W2[(4*k4+3) * 8 + c];
            }
            acc *= LOG2E;                 // fold log2(e) for exp2 inner loop
            short hi = f2bf(acc);
            short lo = f2bf(acc - bf2f(hi));
            fgS[1][rr][c] = hi; fgS[1][rr][c + 8] = lo;
            fgS[1][rr][c + 16] = hi; fgS[1][rr][c + 24] = 0;
        }
    }
    // phase 2: h — thread (c = tid&31, rbase = tid>>5) covers rows rbase, rbase+16
    {
        const int c = tid & 31;
        const int rbase = tid >> 5;
        #pragma unroll
        for (int s = 0; s < 2; ++s) {
            int rr = rbase + s * 16;
            const float4* xr4 = (const float4*)(xS + rr * XPAD);
            float acc = b3[c];
            #pragma unroll
            for (int k4 = 0; k4 < 16; ++k4) {
                float4 xv = xr4[k4];
                acc += xv.x * W3[(4*k4+0) * 32 + c] + xv.y * W3[(4*k4+1) * 32 + c]
                     + xv.z * W3[(4*k4+2) * 32 + c] + xv.w * W3[(4*k4+3) * 32 + c];
            }
            int np = ((rr & 15) >> 2) * 8 + (rr & 3) + ((rr >> 4) & 1) * 4;
            hS[c][np] = f2bf(acc);
        }
    }
    __syncthreads();

    // coalesced write-out (dwords)
    ((int*)(fx + (size_t)r0 * 32))[tid] = ((const int*)fgS[0])[tid];
    ((int*)(gx + (size_t)r0 * 32))[tid] = ((const int*)fgS[1])[tid];
    {
        const int b  = r0 / NTOK;
        const int n0 = r0 - b * NTOK;
        const int kt = n0 >> 5;               // key tile within batch
        const int c  = tid >> 4;              // v = 0..31
        const int d  = tid & 15;              // dword within 64B v-row
        ((int*)(hTi + ((size_t)(b * NKTILE + kt)) * 1024))[c * 16 + d] =
            ((const int*)&hS[c][0])[d];
    }
}

// ---------------------------------------------------------------------------
// Kernel 2: MFMA flash attention, Q=64/wave, 4 waves/block (R15 structure).
// R16: KS=4 — 1152 blocks x 4 waves = 18 waves/CU offered (>= ~16/CU VGPR-
// capped residency), atomics halved, NKT=18 amortizes prologue 2x.
// EXPPACK truncates to bf16 (no +0x8000): -32 VALU/tile; the truncation bias
// is shared by P and l (l-MFMA uses the same P) so it cancels in o/l.
// QK transposed (A=f-ext, B=g-ext); post-exp2 P registers ARE the PV A-frag
// under the k' permutation (R8). Zero in-loop LDS; l via MFMA (B=ones).
// launch_bounds(256,4): VGPR cap 128 (NOT the R9/R10 min-waves>=8 spill trap).
// Grid: QTB*KS = 288*4 = 1152 blocks x 256 threads.
// ---------------------------------------------------------------------------
__global__ __launch_bounds__(256, 4) void attn_kernel(
    const short* __restrict__ fx, const short* __restrict__ gx,
    const short* __restrict__ hTi,
    float* __restrict__ l_acc, float* __restrict__ o_acc)
{
    __shared__ float red[64 * 33];            // epilogue-only, 8448 B

    const int tid  = threadIdx.x;
    const int wave = tid >> 6;                // 0..3
    const int lane = tid & 63;
    const int col  = lane & 15;
    const int quad = lane >> 4;

    const int blk = blockIdx.x;
    const int qt  = blk % QTB;                // query tile 0..287
    const int ks  = blk / QTB;                // key split 0..3
    const int b   = qt / (QTB / BATCH);       // batch
    const int qbase   = (qt % (QTB / BATCH)) * 64;
    const int rowbase = b * NTOK + qbase;

    // persistent B-operands for QK: g-ext for 4 query sub-tiles
    const bf16x8 agA = *(const bf16x8*)(gx + (size_t)(rowbase + col) * 32 + quad * 8);
    const bf16x8 agB = *(const bf16x8*)(gx + (size_t)(rowbase + 16 + col) * 32 + quad * 8);
    const bf16x8 agC = *(const bf16x8*)(gx + (size_t)(rowbase + 32 + col) * 32 + quad * 8);
    const bf16x8 agD = *(const bf16x8*)(gx + (size_t)(rowbase + 48 + col) * 32 + quad * 8);

    bf16x8 ones;
    #pragma unroll
    for (int j = 0; j < 8; ++j) ones[j] = (short)0x3F80;   // bf16 1.0

    f32x4 oA0 = {0,0,0,0}, oA1 = {0,0,0,0};
    f32x4 oB0 = {0,0,0,0}, oB1 = {0,0,0,0};
    f32x4 oC0 = {0,0,0,0}, oC1 = {0,0,0,0};
    f32x4 oD0 = {0,0,0,0}, oD1 = {0,0,0,0};
    f32x4 lfA = {0,0,0,0}, lfB = {0,0,0,0};
    f32x4 lfC = {0,0,0,0}, lfD = {0,0,0,0};
    const f32x4 zero4 = {0,0,0,0};

    const int kstart = ks * KEYS_PER_BLOCK + wave * KEYS_PER_WAVE;
    const short* fbase = fx + ((size_t)b * NTOK + kstart) * 32;
    const short* hbase = hTi + ((size_t)(b * NKTILE) + (kstart >> 5)) * 1024
                             + col * 32 + quad * 8;

    // preload tile 0
    bf16x8 fa0 = *(const bf16x8*)(fbase + (size_t)col * 32 + quad * 8);
    bf16x8 fa1 = *(const bf16x8*)(fbase + (size_t)(16 + col) * 32 + quad * 8);
    bf16x8 hb0 = *(const bf16x8*)(hbase);
    bf16x8 hb1 = *(const bf16x8*)(hbase + 512);

    union PU { int i[4]; bf16x8 v; };

    #define EXPPACK(T0, T1, P)                                                  \
    {                                                                           \
        float e0 = __builtin_amdgcn_exp2f(T0[0]), e1 = __builtin_amdgcn_exp2f(T0[1]); \
        float e2 = __builtin_amdgcn_exp2f(T0[2]), e3 = __builtin_amdgcn_exp2f(T0[3]); \
        float e4 = __builtin_amdgcn_exp2f(T1[0]), e5 = __builtin_amdgcn_exp2f(T1[1]); \
        float e6 = __builtin_amdgcn_exp2f(T1[2]), e7 = __builtin_amdgcn_exp2f(T1[3]); \
        P.i[0] = (int)__builtin_amdgcn_perm((unsigned)__float_as_int(e1),       \
                                            (unsigned)__float_as_int(e0), 0x07060302u); \
        P.i[1] = (int)__builtin_amdgcn_perm((unsigned)__float_as_int(e3),       \
                                            (unsigned)__float_as_int(e2), 0x07060302u); \
        P.i[2] = (int)__builtin_amdgcn_perm((unsigned)__float_as_int(e5),       \
                                            (unsigned)__float_as_int(e4), 0x07060302u); \
        P.i[3] = (int)__builtin_amdgcn_perm((unsigned)__float_as_int(e7),       \
                                            (unsigned)__float_as_int(e6), 0x07060302u); \
    }

    for (int t = 0; t < NKT; ++t) {
        // QK transposed for all 4 sub-tiles: lane holds S[q=col][k=quad*4+r]
        f32x4 tA0 = __builtin_amdgcn_mfma_f32_16x16x32_bf16(fa0, agA, zero4, 0, 0, 0);
        f32x4 tA1 = __builtin_amdgcn_mfma_f32_16x16x32_bf16(fa1, agA, zero4, 0, 0, 0);
        f32x4 tB0 = __builtin_amdgcn_mfma_f32_16x16x32_bf16(fa0, agB, zero4, 0, 0, 0);
        f32x4 tB1 = __builtin_amdgcn_mfma_f32_16x16x32_bf16(fa1, agB, zero4, 0, 0, 0);
        f32x4 tC0 = __builtin_amdgcn_mfma_f32_16x16x32_bf16(fa0, agC, zero4, 0, 0, 0);
        f32x4 tC1 = __builtin_amdgcn_mfma_f32_16x16x32_bf16(fa1, agC, zero4, 0, 0, 0);
        f32x4 tD0 = __builtin_amdgcn_mfma_f32_16x16x32_bf16(fa0, agD, zero4, 0, 0, 0);
        f32x4 tD1 = __builtin_amdgcn_mfma_f32_16x16x32_bf16(fa1, agD, zero4, 0, 0, 0);

        // prefetch tile t+1 (clamped; discarded on last iter)
        const int kn = (t + 1 < NKT) ? (t + 1) : 0;
        bf16x8 nf0 = *(const bf16x8*)(fbase + (size_t)(kn * KT + col) * 32 + quad * 8);
        bf16x8 nf1 = *(const bf16x8*)(fbase + (size_t)(kn * KT + 16 + col) * 32 + quad * 8);
        bf16x8 nh0 = *(const bf16x8*)(hbase + kn * 1024);
        bf16x8 nh1 = *(const bf16x8*)(hbase + kn * 1024 + 512);

        // exp2 + truncate-pack (P registers ARE the PV A-frag), then PV + l
        PU pA, pB, pC, pD;
        EXPPACK(tA0, tA1, pA)
        EXPPACK(tB0, tB1, pB)
        oA0 = __builtin_amdgcn_mfma_f32_16x16x32_bf16(pA.v, hb0, oA0, 0, 0, 0);
        oA1 = __builtin_amdgcn_mfma_f32_16x16x32_bf16(pA.v, hb1, oA1, 0, 0, 0);
        lfA = __builtin_amdgcn_mfma_f32_16x16x32_bf16(pA.v, ones, lfA, 0, 0, 0);
        oB0 = __builtin_amdgcn_mfma_f32_16x16x32_bf16(pB.v, hb0, oB0, 0, 0, 0);
        oB1 = __builtin_amdgcn_mfma_f32_16x16x32_bf16(pB.v, hb1, oB1, 0, 0, 0);
        lfB = __builtin_amdgcn_mfma_f32_16x16x32_bf16(pB.v, ones, lfB, 0, 0, 0);
        EXPPACK(tC0, tC1, pC)
        EXPPACK(tD0, tD1, pD)
        oC0 = __builtin_amdgcn_mfma_f32_16x16x32_bf16(pC.v, hb0, oC0, 0, 0, 0);
        oC1 = __builtin_amdgcn_mfma_f32_16x16x32_bf16(pC.v, hb1, oC1, 0, 0, 0);
        lfC = __builtin_amdgcn_mfma_f32_16x16x32_bf16(pC.v, ones, lfC, 0, 0, 0);
        oD0 = __builtin_amdgcn_mfma_f32_16x16x32_bf16(pD.v, hb0, oD0, 0, 0, 0);
        oD1 = __builtin_amdgcn_mfma_f32_16x16x32_bf16(pD.v, hb1, oD1, 0, 0, 0);
        lfD = __builtin_amdgcn_mfma_f32_16x16x32_bf16(pD.v, ones, lfD, 0, 0, 0);

        fa0 = nf0; fa1 = nf1; hb0 = nh0; hb1 = nh1;
    }
    #undef EXPPACK

    // 3-round cross-wave merge in one 8.4 KB buffer: wave w publishes,
    // wave 0 accumulates into registers; then wave 0 issues global atomics.
    for (int w = 1; w < 4; ++w) {
        if (wave == w) {
            #pragma unroll
            for (int r = 0; r < 4; ++r) {
                int q = quad * 4 + r;
                red[(q)      * 33 + col]      = oA0[r];
                red[(q)      * 33 + 16 + col] = oA1[r];
                red[(q + 16) * 33 + col]      = oB0[r];
                red[(q + 16) * 33 + 16 + col] = oB1[r];
                red[(q + 32) * 33 + col]      = oC0[r];
                red[(q + 32) * 33 + 16 + col] = oC1[r];
                red[(q + 48) * 33 + col]      = oD0[r];
                red[(q + 48) * 33 + 16 + col] = oD1[r];
            }
            if (col == 0) {
                #pragma unroll
                for (int r = 0; r < 4; ++r) {
                    int q = quad * 4 + r;
                    red[(q)      * 33 + 32] = lfA[r];
                    red[(q + 16) * 33 + 32] = lfB[r];
                    red[(q + 32) * 33 + 32] = lfC[r];
                    red[(q + 48) * 33 + 32] = lfD[r];
                }
            }
        }
        __syncthreads();
        if (wave == 0) {
            #pragma unroll
            for (int r = 0; r < 4; ++r) {
                int q = quad * 4 + r;
                oA0[r] += red[(q)      * 33 + col];
                oA1[r] += red[(q)      * 33 + 16 + col];
                oB0[r] += red[(q + 16) * 33 + col];
                oB1[r] += red[(q + 16) * 33 + 16 + col];
                oC0[r] += red[(q + 32) * 33 + col];
                oC1[r] += red[(q + 32) * 33 + 16 + col];
                oD0[r] += red[(q + 48) * 33 + col];
                oD1[r] += red[(q + 48) * 33 + 16 + col];
                lfA[r] += red[(q)      * 33 + 32];
                lfB[r] += red[(q + 16) * 33 + 32];
                lfC[r] += red[(q + 32) * 33 + 32];
                lfD[r] += red[(q + 48) * 33 + 32];
            }
        }
        __syncthreads();
    }
    if (wave == 0) {
        #pragma unroll
        for (int r = 0; r < 4; ++r) {
            int q = quad * 4 + r;
            atomicAdd(&o_acc[(size_t)(rowbase + q)      * 32 + col],      oA0[r]);
            atomicAdd(&o_acc[(size_t)(rowbase + q)      * 32 + 16 + col], oA1[r]);
            atomicAdd(&o_acc[(size_t)(rowbase + q + 16) * 32 + col],      oB0[r]);
            atomicAdd(&o_acc[(size_t)(rowbase + q + 16) * 32 + 16 + col], oB1[r]);
            atomicAdd(&o_acc[(size_t)(rowbase + q + 32) * 32 + col],      oC0[r]);
            atomicAdd(&o_acc[(size_t)(rowbase + q + 32) * 32 + 16 + col], oC1[r]);
            atomicAdd(&o_acc[(size_t)(rowbase + q + 48) * 32 + col],      oD0[r]);
            atomicAdd(&o_acc[(size_t)(rowbase + q + 48) * 32 + 16 + col], oD1[r]);
        }
        if (col == 0) {
            #pragma unroll
            for (int r = 0; r < 4; ++r) {
                int q = quad * 4 + r;
                atomicAdd(&l_acc[rowbase + q],      lfA[r]);
                atomicAdd(&l_acc[rowbase + q + 16], lfB[r]);
                atomicAdd(&l_acc[rowbase + q + 32], lfC[r]);
                atomicAdd(&l_acc[rowbase + q + 48], lfD[r]);
            }
        }
    }
}

// ---------------------------------------------------------------------------
// Kernel 3: normalize + output projection + residual (fp32 weights).
// One wave per query: o[k] = o_acc/l ; out = gamma*(o@W4 + b4) + x
// ---------------------------------------------------------------------------
__global__ __launch_bounds__(256) void merge_kernel(
    const float* __restrict__ l_acc, const float* __restrict__ o_acc,
    const float* __restrict__ x,
    const float* __restrict__ W4, const float* __restrict__ b4,
    const float* __restrict__ gamma, float* __restrict__ out)
{
    __shared__ float oS[4][DV];
    int wave = threadIdx.x >> 6;
    int lane = threadIdx.x & 63;
    int row  = blockIdx.x * 4 + wave;     // < 18432 exactly

    float invL = 1.f / l_acc[row];
    if (lane < DV) {
        oS[wave][lane] = o_acc[(size_t)row * DV + lane] * invL;
    }
    __syncthreads();

    float dot = b4[lane];
    #pragma unroll
    for (int k = 0; k < DV; ++k) dot += oS[wave][k] * W4[k * 64 + lane];
    float gm  = gamma[0];
    float res = x[(size_t)row * 64 + lane];
    out[(size_t)row * 64 + lane] = gm * dot + res;
}

// ---------------------------------------------------------------------------
extern "C" void kernel_launch(void* const* d_in, const int* in_sizes, int n_in,
                              void* d_out, int out_size, void* d_ws, size_t ws_size,
                              hipStream_t stream) {
    const float* x     = (const float*)d_in[0];
    const float* W1    = (const float*)d_in[1];
    const float* b1    = (const float*)d_in[2];
    const float* W2    = (const float*)d_in[3];
    const float* b2    = (const float*)d_in[4];
    const float* W3    = (const float*)d_in[5];
    const float* b3    = (const float*)d_in[6];
    const float* W4    = (const float*)d_in[7];
    const float* b4    = (const float*)d_in[8];
    const float* gamma = (const float*)d_in[9];
    float* out = (float*)d_out;

    // Workspace: fx/gx/hTi bf16 (1.18 MB each) + l_acc + o_acc = 5.97 MB total
    short* fx    = (short*)d_ws;                       // 589824 shorts
    short* gx    = fx + (size_t)ROWS * 32;             // 589824 shorts
    short* hTi   = gx + (size_t)ROWS * 32;             // 589824 shorts
    float* l_acc = (float*)(hTi + (size_t)ROWS * 32);  // 18432 floats
    float* o_acc = l_acc + ROWS;                       // 589824 floats

    // proj (+ zeroing of l_acc/o_acc): 576 blocks x 512 threads
    proj_kernel<<<ROWS / PB, 512, 0, stream>>>(
        x, W1, b1, W2, b2, W3, b3, fx, gx, hTi, (float4*)l_acc);

    // attention: 288 query-tiles (64 q) x 4 key-splits = 1152 blocks x 4 waves
    attn_kernel<<<QTB * KS, 256, 0, stream>>>(fx, gx, hTi, l_acc, o_acc);

    // merge: 18432 queries / 4 waves per block
    merge_kernel<<<ROWS / 4, 256, 0, stream>>>(l_acc, o_acc, x, W4, b4, gamma, out);
}